// Round 1
// baseline (400.770 us; speedup 1.0000x reference)
//
#include <hip/hip_runtime.h>
#include <stdint.h>

// MHA fwd: B=4,S=2048,E=1024,H=16,D=64. fp32 in/out, bf16 MFMA internally.
// Pipeline: pack(X,Wqkv,Wo->bf16) -> GEMM1 (QKV proj, writes Q*0.125,K,[s][d], V^T [d][s])
//           -> flash attn (causal) -> GEMM2 (out proj, fp32 out).

typedef float   f32x4  __attribute__((ext_vector_type(4)));
typedef __bf16  bf16x8 __attribute__((ext_vector_type(8)));
typedef short   short8 __attribute__((ext_vector_type(8)));
typedef unsigned short ushort4v __attribute__((ext_vector_type(4)));

typedef __attribute__((address_space(1))) void GV;
typedef __attribute__((address_space(3))) void LV;

#define DEVI static __device__ __forceinline__

DEVI unsigned short f2bf(float f){
  unsigned u = __float_as_uint(f);
  unsigned r = u + 0x7fffu + ((u>>16)&1u);
  return (unsigned short)(r>>16);
}

DEVI void gl_lds16(const void* g, void* l){
  // 16B per lane, dest = wave-uniform LDS base + lane*16
  __builtin_amdgcn_global_load_lds((GV*)g, (LV*)l, 16, 0, 0);
}

// ---------------- pack kernels ----------------
__global__ __launch_bounds__(256) void pack_x(const float* __restrict__ X,
                                              short* __restrict__ Xb){
  int i = blockIdx.x*256 + threadIdx.x;          // 1,048,576 threads, 8 elems each
  const float4* p = (const float4*)(X + (size_t)i*8);
  float4 a = p[0], b = p[1];
  short8 o;
  o[0]=(short)f2bf(a.x); o[1]=(short)f2bf(a.y); o[2]=(short)f2bf(a.z); o[3]=(short)f2bf(a.w);
  o[4]=(short)f2bf(b.x); o[5]=(short)f2bf(b.y); o[6]=(short)f2bf(b.z); o[7]=(short)f2bf(b.w);
  *(short8*)(Xb + (size_t)i*8) = o;
}

// Wp[n][k], n = which*1024 + h*64 + d, k = e.  Wq/Wk/Wv are (H=16, E=1024, D=64).
__global__ __launch_bounds__(256) void pack_wqkv(const float* __restrict__ Wq,
                                                 const float* __restrict__ Wk,
                                                 const float* __restrict__ Wv,
                                                 short* __restrict__ Wp){
  int t = blockIdx.x*256 + threadIdx.x;          // n*128 + kc ; n<3072, kc<128
  int n = t >> 7, kc = t & 127;
  int which = n >> 10, hd = n & 1023, h = hd >> 6, d = hd & 63;
  const float* W = which==0 ? Wq : (which==1 ? Wk : Wv);
  const float* src = W + ((size_t)h*1024 + kc*8)*64 + d;
  short8 o;
  #pragma unroll
  for (int j=0;j<8;++j) o[j] = (short)f2bf(src[(size_t)j*64]);
  *(short8*)(Wp + (size_t)n*1024 + kc*8) = o;
}

// WoT[n][k] = Wo[k][n]; Wo is (1024,1024)
__global__ __launch_bounds__(256) void pack_wo(const float* __restrict__ Wo,
                                               short* __restrict__ WoT){
  int t = blockIdx.x*256 + threadIdx.x;          // n*128 + kc ; n<1024
  int n = t >> 7, kc = t & 127;
  const float* src = Wo + (size_t)(kc*8)*1024 + n;
  short8 o;
  #pragma unroll
  for (int j=0;j<8;++j) o[j] = (short)f2bf(src[(size_t)j*1024]);
  *(short8*)(WoT + (size_t)n*1024 + kc*8) = o;
}

// ---------------- GEMM: C[M=8192][N] = A[M][1024] * Bt[N][1024]^T ----------------
// 128x128 tile, BK=64, 4 waves in 2x2, each wave 64x64 (4x4 of 16x16x32 MFMA).
// LDS tiles [128 rows][128 bytes] with XOR swizzle byte ^= ((row&7)<<4).
template<int MODE>   // 0: QKV epilogue, 1: out-proj epilogue
__global__ __launch_bounds__(256)
void gemm128(const short* __restrict__ A, const short* __restrict__ Bt,
             const float* __restrict__ b0, const float* __restrict__ b1,
             const float* __restrict__ b2,
             short* __restrict__ Qb, short* __restrict__ Kb, short* __restrict__ Vtb,
             float* __restrict__ Out)
{
  __shared__ __align__(16) char smA[128*128];
  __shared__ __align__(16) char smB[128*128];
  const int K2 = 2048;                       // K*2 bytes
  int t = threadIdx.x, lane = t & 63, wid = t >> 6;
  int wr = wid >> 1, wc = wid & 1;
  int l15 = lane & 15, l4 = lane >> 4;
  int bm = blockIdx.x & 63, bn = blockIdx.x >> 6;   // M/128 == 64 for both GEMMs
  size_t abase = (size_t)bm * 128 * K2;
  size_t bbase = (size_t)bn * 128 * K2;

  f32x4 acc[4][4] = {};

  for (int kt = 0; kt < 16; ++kt){
    int kb = kt * 128;                       // k-offset in bytes
    #pragma unroll
    for (int c = 0; c < 4; ++c){
      int x = c*4096 + t*16;
      int r = x >> 7, z = x & 127;
      int zs = z ^ ((r & 7) << 4);
      gl_lds16((const char*)A  + abase + (size_t)r*K2 + kb + zs, smA + c*4096 + wid*1024);
      gl_lds16((const char*)Bt + bbase + (size_t)r*K2 + kb + zs, smB + c*4096 + wid*1024);
    }
    __syncthreads();
    #pragma unroll
    for (int kk = 0; kk < 2; ++kk){
      bf16x8 af[4], bfr[4];
      int cb = kk*64 + l4*16;
      #pragma unroll
      for (int i = 0; i < 4; ++i){
        int ra = wr*64 + i*16 + l15;
        af[i]  = *(const bf16x8*)(smA + ra*128 + (cb ^ ((ra&7)<<4)));
        int rb = wc*64 + i*16 + l15;
        bfr[i] = *(const bf16x8*)(smB + rb*128 + (cb ^ ((rb&7)<<4)));
      }
      #pragma unroll
      for (int i = 0; i < 4; ++i)
        #pragma unroll
        for (int j = 0; j < 4; ++j)
          acc[i][j] = __builtin_amdgcn_mfma_f32_16x16x32_bf16(af[i], bfr[j], acc[i][j], 0, 0, 0);
    }
    __syncthreads();
  }

  // epilogue. C layout: col = l15 (n dir), row = l4*4 + r (m dir)
  #pragma unroll
  for (int i = 0; i < 4; ++i){
    int mbase = bm*128 + wr*64 + i*16 + l4*4;
    #pragma unroll
    for (int j = 0; j < 4; ++j){
      int n = bn*128 + wc*64 + j*16 + l15;
      if (MODE == 0){
        int which = n >> 10, hd = n & 1023, h = hd >> 6, d = hd & 63;
        const float* bp = which==0 ? b0 : (which==1 ? b1 : b2);
        float bias = bp[hd];
        int b = mbase >> 11, sbase = mbase & 2047;
        size_t bh = (size_t)(b*16 + h);
        if (which == 2){
          ushort4v pv;
          #pragma unroll
          for (int r = 0; r < 4; ++r) pv[r] = f2bf(acc[i][j][r] + bias);
          *(ushort4v*)(Vtb + (bh*64 + d)*2048 + sbase) = pv;
        } else {
          short* dst = (which==0 ? Qb : Kb) + bh*2048*64;
          float sc = which==0 ? 0.125f : 1.0f;
          #pragma unroll
          for (int r = 0; r < 4; ++r)
            dst[(size_t)(sbase + r)*64 + d] = (short)f2bf((acc[i][j][r] + bias) * sc);
        }
      } else {
        float bias = b0[n];
        #pragma unroll
        for (int r = 0; r < 4; ++r)
          Out[(size_t)(mbase + r)*1024 + n] = acc[i][j][r] + bias;
      }
    }
  }
}

// ---------------- causal flash attention ----------------
// grid: (B*H)*32 blocks; block handles 64 q-rows of one (b,h); 4 waves x 16 rows.
// K tile [64 s][128B] swizzled; V^T tile [64 d][128B] swizzled; P per-wave [16][128B].
__global__ __launch_bounds__(256)
void attn(const short* __restrict__ Qb, const short* __restrict__ Kb,
          const short* __restrict__ Vtb, short* __restrict__ Ob)
{
  __shared__ __align__(16) char smK[64*128];
  __shared__ __align__(16) char smV[64*128];
  __shared__ __align__(16) char smP[4][16*128];
  int t = threadIdx.x, lane = t & 63, wid = t >> 6;
  int l15 = lane & 15, l4 = lane >> 4;
  int bh = blockIdx.x >> 5, qb = blockIdx.x & 31;
  int b = bh >> 4, h = bh & 15;
  int q0 = qb * 64;
  const char* Qh = (const char*)(Qb + (size_t)bh*2048*64);
  const char* Kh = (const char*)(Kb + (size_t)bh*2048*64);
  const char* Vh = (const char*)(Vtb + (size_t)bh*64*2048);

  // Q fragments (held in registers for whole block)
  int qrow = q0 + wid*16 + l15;
  bf16x8 qf[2];
  qf[0] = *(const bf16x8*)(Qh + (size_t)qrow*128 + l4*16);
  qf[1] = *(const bf16x8*)(Qh + (size_t)qrow*128 + 64 + l4*16);

  f32x4 oacc[4] = {};
  float mrow[4], lrow[4];
  #pragma unroll
  for (int r = 0; r < 4; ++r){ mrow[r] = -1e30f; lrow[r] = 0.f; }

  const float L2E = 1.44269504f;
  int nkt = qb + 1;
  for (int kt = 0; kt < nkt; ++kt){
    // stage K tile (8KB, contiguous in global) and V^T tile (8KB, rows stride 4096B)
    #pragma unroll
    for (int c = 0; c < 2; ++c){
      int x = c*4096 + t*16;
      int r = x >> 7, z = x & 127;
      int zs = z ^ ((r & 7) << 4);
      gl_lds16(Kh + (size_t)kt*8192 + (size_t)r*128 + zs, smK + c*4096 + wid*1024);
    }
    #pragma unroll
    for (int c = 0; c < 2; ++c){
      int x = c*4096 + t*16;
      int d = x >> 7, z = x & 127;
      int zs = z ^ ((d & 7) << 4);
      gl_lds16(Vh + (size_t)d*4096 + kt*128 + zs, smV + c*4096 + wid*1024);
    }
    __syncthreads();

    // S = Q K^T  (4 n-subtiles of 16)
    f32x4 sa[4];
    #pragma unroll
    for (int nt = 0; nt < 4; ++nt){
      f32x4 a = {};
      #pragma unroll
      for (int kk = 0; kk < 2; ++kk){
        int rb = nt*16 + l15;
        int cb = kk*64 + l4*16;
        bf16x8 kf = *(const bf16x8*)(smK + rb*128 + (cb ^ ((rb&7)<<4)));
        a = __builtin_amdgcn_mfma_f32_16x16x32_bf16(qf[kk], kf, a, 0, 0, 0);
      }
      sa[nt] = a;
    }
    // causal mask on diagonal tile
    if (kt == qb){
      #pragma unroll
      for (int nt = 0; nt < 4; ++nt)
        #pragma unroll
        for (int r = 0; r < 4; ++r){
          int n = kt*64 + nt*16 + l15;
          int m = q0 + wid*16 + l4*4 + r;
          if (n > m) sa[nt][r] = -1e30f;
        }
    }
    // online softmax (rows live in 16-lane groups; reduce via shfl_xor)
    #pragma unroll
    for (int r = 0; r < 4; ++r){
      float mx = fmaxf(fmaxf(sa[0][r], sa[1][r]), fmaxf(sa[2][r], sa[3][r]));
      #pragma unroll
      for (int off = 1; off < 16; off <<= 1) mx = fmaxf(mx, __shfl_xor(mx, off));
      float mnew = fmaxf(mrow[r], mx);
      float sc = exp2f((mrow[r] - mnew) * L2E);
      mrow[r] = mnew;
      float rs = 0.f;
      #pragma unroll
      for (int nt = 0; nt < 4; ++nt){
        float p = exp2f((sa[nt][r] - mnew) * L2E);
        sa[nt][r] = p; rs += p;
      }
      #pragma unroll
      for (int off = 1; off < 16; off <<= 1) rs += __shfl_xor(rs, off);
      lrow[r] = lrow[r]*sc + rs;
      #pragma unroll
      for (int dt = 0; dt < 4; ++dt) oacc[dt][r] *= sc;
    }
    // P -> LDS (wave-private, swizzled), then PV
    char* Pw = smP[wid];
    #pragma unroll
    for (int nt = 0; nt < 4; ++nt)
      #pragma unroll
      for (int r = 0; r < 4; ++r){
        int pr = l4*4 + r;
        int pcb = (nt*16 + l15)*2;
        *(unsigned short*)(Pw + pr*128 + (pcb ^ ((pr&7)<<4))) = f2bf(sa[nt][r]);
      }
    #pragma unroll
    for (int kk = 0; kk < 2; ++kk){
      int pcb = kk*64 + l4*16;
      bf16x8 pf = *(const bf16x8*)(Pw + l15*128 + (pcb ^ ((l15&7)<<4)));
      #pragma unroll
      for (int dt = 0; dt < 4; ++dt){
        int vr = dt*16 + l15;
        bf16x8 vf = *(const bf16x8*)(smV + vr*128 + (pcb ^ ((vr&7)<<4)));
        oacc[dt] = __builtin_amdgcn_mfma_f32_16x16x32_bf16(pf, vf, oacc[dt], 0, 0, 0);
      }
    }
    __syncthreads();
  }

  // write O (concat layout [b][s][h*64+d]) in bf16
  #pragma unroll
  for (int dt = 0; dt < 4; ++dt)
    #pragma unroll
    for (int r = 0; r < 4; ++r){
      int s = q0 + wid*16 + l4*4 + r;
      int col = h*64 + dt*16 + l15;
      float v = oacc[dt][r] / lrow[r];
      Ob[((size_t)(b*2048 + s))*1024 + col] = (short)f2bf(v);
    }
}

// ---------------- launch ----------------
extern "C" void kernel_launch(void* const* d_in, const int* in_sizes, int n_in,
                              void* d_out, int out_size, void* d_ws, size_t ws_size,
                              hipStream_t stream)
{
  const float* X  = (const float*)d_in[0];
  const float* Wq = (const float*)d_in[1];
  const float* Wk = (const float*)d_in[2];
  const float* Wv = (const float*)d_in[3];
  const float* bq = (const float*)d_in[4];
  const float* bk = (const float*)d_in[5];
  const float* bv = (const float*)d_in[6];
  const float* Wo = (const float*)d_in[7];
  const float* bo = (const float*)d_in[8];
  float* Out = (float*)d_out;

  char* ws = (char*)d_ws;
  short* Xbf  = (short*)(ws);                    // 16 MB
  short* Wp   = (short*)(ws + 16777216);         // 6 MB
  short* WoT  = (short*)(ws + 23068672);         // 2 MB
  short* Qb   = (short*)(ws + 25165824);         // 16 MB
  short* Kb   = (short*)(ws + 41943040);         // 16 MB
  short* Vtb  = (short*)(ws + 58720256);         // 16 MB
  short* Ob   = (short*)(ws + 75497472);         // 16 MB  (total ~88 MB)

  pack_x   <<<4096, 256, 0, stream>>>(X, Xbf);
  pack_wqkv<<<1536, 256, 0, stream>>>(Wq, Wk, Wv, Wp);
  pack_wo  <<< 512, 256, 0, stream>>>(Wo, WoT);

  gemm128<0><<<24*64, 256, 0, stream>>>(Xbf, Wp, bq, bk, bv, Qb, Kb, Vtb, nullptr);
  attn      <<<64*32, 256, 0, stream>>>(Qb, Kb, Vtb, Ob);
  gemm128<1><<< 8*64, 256, 0, stream>>>(Ob, WoT, bo, nullptr, nullptr,
                                        nullptr, nullptr, nullptr, Out);
}

// Round 2
// 357.500 us; speedup vs baseline: 1.1210x; 1.1210x over previous
//
#include <hip/hip_runtime.h>
#include <stdint.h>

// MHA fwd: B=4,S=2048,E=1024,H=16,D=64. fp32 in/out, bf16 MFMA internally.
// pack(X,W->bf16) -> GEMM1 (QKV; Q pre-scaled by 0.125*log2e, V stored transposed)
//   -> causal flash attn (LPT block order, double-buffered K/V) -> GEMM2 (out proj).

typedef float   f32x4  __attribute__((ext_vector_type(4)));
typedef __bf16  bf16x8 __attribute__((ext_vector_type(8)));
typedef short   short8 __attribute__((ext_vector_type(8)));
typedef unsigned short ushort4v __attribute__((ext_vector_type(4)));

typedef __attribute__((address_space(1))) void GV;
typedef __attribute__((address_space(3))) void LV;

#define DEVI static __device__ __forceinline__

DEVI unsigned short f2bf(float f){
  unsigned u = __float_as_uint(f);
  unsigned r = u + 0x7fffu + ((u>>16)&1u);
  return (unsigned short)(r>>16);
}

DEVI void gl_lds16(const void* g, void* l){
  __builtin_amdgcn_global_load_lds((GV*)g, (LV*)l, 16, 0, 0);
}

// ---------------- pack kernels ----------------
__global__ __launch_bounds__(256) void pack_x(const float* __restrict__ X,
                                              short* __restrict__ Xb){
  int i = blockIdx.x*256 + threadIdx.x;
  const float4* p = (const float4*)(X + (size_t)i*8);
  float4 a = p[0], b = p[1];
  short8 o;
  o[0]=(short)f2bf(a.x); o[1]=(short)f2bf(a.y); o[2]=(short)f2bf(a.z); o[3]=(short)f2bf(a.w);
  o[4]=(short)f2bf(b.x); o[5]=(short)f2bf(b.y); o[6]=(short)f2bf(b.z); o[7]=(short)f2bf(b.w);
  *(short8*)(Xb + (size_t)i*8) = o;
}

__global__ __launch_bounds__(256) void pack_wqkv(const float* __restrict__ Wq,
                                                 const float* __restrict__ Wk,
                                                 const float* __restrict__ Wv,
                                                 short* __restrict__ Wp){
  int t = blockIdx.x*256 + threadIdx.x;
  int n = t >> 7, kc = t & 127;
  int which = n >> 10, hd = n & 1023, h = hd >> 6, d = hd & 63;
  const float* W = which==0 ? Wq : (which==1 ? Wk : Wv);
  const float* src = W + ((size_t)h*1024 + kc*8)*64 + d;
  short8 o;
  #pragma unroll
  for (int j=0;j<8;++j) o[j] = (short)f2bf(src[(size_t)j*64]);
  *(short8*)(Wp + (size_t)n*1024 + kc*8) = o;
}

__global__ __launch_bounds__(256) void pack_wo(const float* __restrict__ Wo,
                                               short* __restrict__ WoT){
  int t = blockIdx.x*256 + threadIdx.x;
  int n = t >> 7, kc = t & 127;
  const float* src = Wo + (size_t)(kc*8)*1024 + n;
  short8 o;
  #pragma unroll
  for (int j=0;j<8;++j) o[j] = (short)f2bf(src[(size_t)j*1024]);
  *(short8*)(WoT + (size_t)n*1024 + kc*8) = o;
}

// ---------------- GEMM: C[M=8192][N] = A[M][1024] * Bt[N][1024]^T ----------------
template<int MODE>   // 0: QKV epilogue, 1: out-proj epilogue
__global__ __launch_bounds__(256)
void gemm128(const short* __restrict__ A, const short* __restrict__ Bt,
             const float* __restrict__ b0, const float* __restrict__ b1,
             const float* __restrict__ b2,
             short* __restrict__ Qb, short* __restrict__ Kb, short* __restrict__ Vtb,
             float* __restrict__ Out)
{
  __shared__ __align__(16) char smA[128*128];
  __shared__ __align__(16) char smB[128*128];
  const int K2 = 2048;
  int t = threadIdx.x, lane = t & 63, wid = t >> 6;
  int wr = wid >> 1, wc = wid & 1;
  int l15 = lane & 15, l4 = lane >> 4;
  // XCD-aware swizzle (grid divisible by 8 in both uses)
  int nwg = gridDim.x, qd = nwg >> 3;
  int swz = (blockIdx.x & 7) * qd + (blockIdx.x >> 3);
  int bm = swz & 63, bn = swz >> 6;
  size_t abase = (size_t)bm * 128 * K2;
  size_t bbase = (size_t)bn * 128 * K2;

  f32x4 acc[4][4] = {};

  for (int kt = 0; kt < 16; ++kt){
    int kb = kt * 128;
    #pragma unroll
    for (int c = 0; c < 4; ++c){
      int x = c*4096 + t*16;
      int r = x >> 7, z = x & 127;
      int zs = z ^ ((r & 7) << 4);
      gl_lds16((const char*)A  + abase + (size_t)r*K2 + kb + zs, smA + c*4096 + wid*1024);
      gl_lds16((const char*)Bt + bbase + (size_t)r*K2 + kb + zs, smB + c*4096 + wid*1024);
    }
    __syncthreads();
    #pragma unroll
    for (int kk = 0; kk < 2; ++kk){
      bf16x8 af[4], bfr[4];
      int cb = kk*64 + l4*16;
      #pragma unroll
      for (int i = 0; i < 4; ++i){
        int ra = wr*64 + i*16 + l15;
        af[i]  = *(const bf16x8*)(smA + ra*128 + (cb ^ ((ra&7)<<4)));
        int rb = wc*64 + i*16 + l15;
        bfr[i] = *(const bf16x8*)(smB + rb*128 + (cb ^ ((rb&7)<<4)));
      }
      __builtin_amdgcn_s_setprio(1);
      #pragma unroll
      for (int i = 0; i < 4; ++i)
        #pragma unroll
        for (int j = 0; j < 4; ++j)
          acc[i][j] = __builtin_amdgcn_mfma_f32_16x16x32_bf16(af[i], bfr[j], acc[i][j], 0, 0, 0);
      __builtin_amdgcn_s_setprio(0);
    }
    __syncthreads();
  }

  #pragma unroll
  for (int i = 0; i < 4; ++i){
    int mbase = bm*128 + wr*64 + i*16 + l4*4;
    #pragma unroll
    for (int j = 0; j < 4; ++j){
      int n = bn*128 + wc*64 + j*16 + l15;
      if (MODE == 0){
        int which = n >> 10, hd = n & 1023, h = hd >> 6, d = hd & 63;
        const float* bp = which==0 ? b0 : (which==1 ? b1 : b2);
        float bias = bp[hd];
        int b = mbase >> 11, sbase = mbase & 2047;
        size_t bh = (size_t)(b*16 + h);
        if (which == 2){
          ushort4v pv;
          #pragma unroll
          for (int r = 0; r < 4; ++r) pv[r] = f2bf(acc[i][j][r] + bias);
          *(ushort4v*)(Vtb + (bh*64 + d)*2048 + sbase) = pv;
        } else {
          short* dst = (which==0 ? Qb : Kb) + bh*2048*64;
          // Q pre-scaled by 1/sqrt(D) * log2(e) so attn exp uses exp2 directly
          float sc = which==0 ? 0.18033688f : 1.0f;
          #pragma unroll
          for (int r = 0; r < 4; ++r)
            dst[(size_t)(sbase + r)*64 + d] = (short)f2bf((acc[i][j][r] + bias) * sc);
        }
      } else {
        float bias = b0[n];
        #pragma unroll
        for (int r = 0; r < 4; ++r)
          Out[(size_t)(mbase + r)*1024 + n] = acc[i][j][r] + bias;
      }
    }
  }
}

// ---------------- causal flash attention ----------------
// grid: (B*H)*32 blocks; LPT order (long qb first); 4 waves x 16 q-rows;
// double-buffered K/V tiles, one barrier per KV step.
__global__ __launch_bounds__(256)
void attn(const short* __restrict__ Qb, const short* __restrict__ Kb,
          const short* __restrict__ Vtb, short* __restrict__ Ob)
{
  __shared__ __align__(16) char smK[2][8192];
  __shared__ __align__(16) char smV[2][8192];
  __shared__ __align__(16) char smP[4][2048];
  int t = threadIdx.x, lane = t & 63, wid = t >> 6;
  int l15 = lane & 15, l4 = lane >> 4;
  int bh = blockIdx.x >> 5;
  int qb = 31 - (blockIdx.x & 31);           // LPT: longest blocks dispatch first
  int b = bh >> 4, h = bh & 15;
  int q0 = qb * 64;
  const char* Qh = (const char*)(Qb + (size_t)bh*2048*64);
  const char* Kh = (const char*)(Kb + (size_t)bh*2048*64);
  const char* Vh = (const char*)(Vtb + (size_t)bh*64*2048);

  int qrow = q0 + wid*16 + l15;
  bf16x8 qf[2];
  qf[0] = *(const bf16x8*)(Qh + (size_t)qrow*128 + l4*16);
  qf[1] = *(const bf16x8*)(Qh + (size_t)qrow*128 + 64 + l4*16);

  f32x4 oacc[4] = {};
  float mrow[4], lrow[4];
  #pragma unroll
  for (int r = 0; r < 4; ++r){ mrow[r] = -1e30f; lrow[r] = 0.f; }

  int nkt = qb + 1;

  // prologue: stage tile 0 into buffer 0
  {
    #pragma unroll
    for (int c = 0; c < 2; ++c){
      int x = c*4096 + t*16;
      int r = x >> 7, z = x & 127;
      int zs = z ^ ((r & 7) << 4);
      gl_lds16(Kh + (size_t)r*128 + zs, smK[0] + c*4096 + wid*1024);
      gl_lds16(Vh + (size_t)r*4096 + zs, smV[0] + c*4096 + wid*1024);
    }
  }
  __syncthreads();

  for (int kt = 0; kt < nkt; ++kt){
    int cur = kt & 1;
    // prefetch next tile into the other buffer (lands during compute)
    if (kt + 1 < nkt){
      int nxt = cur ^ 1;
      #pragma unroll
      for (int c = 0; c < 2; ++c){
        int x = c*4096 + t*16;
        int r = x >> 7, z = x & 127;
        int zs = z ^ ((r & 7) << 4);
        gl_lds16(Kh + (size_t)(kt+1)*8192 + (size_t)r*128 + zs, smK[nxt] + c*4096 + wid*1024);
        gl_lds16(Vh + (size_t)r*4096 + (size_t)(kt+1)*128 + zs, smV[nxt] + c*4096 + wid*1024);
      }
    }

    // S = Q K^T (already in log2 units; Q carries 0.125*log2e)
    f32x4 sa[4];
    #pragma unroll
    for (int nt = 0; nt < 4; ++nt){
      f32x4 a = {};
      __builtin_amdgcn_s_setprio(1);
      #pragma unroll
      for (int kk = 0; kk < 2; ++kk){
        int rb = nt*16 + l15;
        int cb = kk*64 + l4*16;
        bf16x8 kf = *(const bf16x8*)(smK[cur] + rb*128 + (cb ^ ((rb&7)<<4)));
        a = __builtin_amdgcn_mfma_f32_16x16x32_bf16(qf[kk], kf, a, 0, 0, 0);
      }
      __builtin_amdgcn_s_setprio(0);
      sa[nt] = a;
    }
    if (kt == qb){
      #pragma unroll
      for (int nt = 0; nt < 4; ++nt)
        #pragma unroll
        for (int r = 0; r < 4; ++r){
          int n = kt*64 + nt*16 + l15;
          int m = q0 + wid*16 + l4*4 + r;
          if (n > m) sa[nt][r] = -1e30f;
        }
    }
    // online softmax: rows live in 16-lane groups
    #pragma unroll
    for (int r = 0; r < 4; ++r){
      float mx = fmaxf(fmaxf(sa[0][r], sa[1][r]), fmaxf(sa[2][r], sa[3][r]));
      #pragma unroll
      for (int off = 1; off < 16; off <<= 1) mx = fmaxf(mx, __shfl_xor(mx, off));
      float mnew = fmaxf(mrow[r], mx);
      float sc = exp2f(mrow[r] - mnew);
      mrow[r] = mnew;
      float rs = 0.f;
      #pragma unroll
      for (int nt = 0; nt < 4; ++nt){
        float p = exp2f(sa[nt][r] - mnew);
        sa[nt][r] = p; rs += p;
      }
      #pragma unroll
      for (int off = 1; off < 16; off <<= 1) rs += __shfl_xor(rs, off);
      lrow[r] = lrow[r]*sc + rs;
      #pragma unroll
      for (int dt = 0; dt < 4; ++dt) oacc[dt][r] *= sc;
    }
    // P -> wave-private LDS, then PV
    char* Pw = smP[wid];
    #pragma unroll
    for (int nt = 0; nt < 4; ++nt)
      #pragma unroll
      for (int r = 0; r < 4; ++r){
        int pr = l4*4 + r;
        int pcb = (nt*16 + l15)*2;
        *(unsigned short*)(Pw + pr*128 + (pcb ^ ((pr&7)<<4))) = f2bf(sa[nt][r]);
      }
    #pragma unroll
    for (int kk = 0; kk < 2; ++kk){
      int pcb = kk*64 + l4*16;
      bf16x8 pf = *(const bf16x8*)(Pw + l15*128 + (pcb ^ ((l15&7)<<4)));
      __builtin_amdgcn_s_setprio(1);
      #pragma unroll
      for (int dt = 0; dt < 4; ++dt){
        int vr = dt*16 + l15;
        bf16x8 vf = *(const bf16x8*)(smV[cur] + vr*128 + (pcb ^ ((vr&7)<<4)));
        oacc[dt] = __builtin_amdgcn_mfma_f32_16x16x32_bf16(pf, vf, oacc[dt], 0, 0, 0);
      }
      __builtin_amdgcn_s_setprio(0);
    }
    // single barrier per step: drains this step's prefetch (landed under compute)
    // and protects buffers for the next overwrite
    __syncthreads();
  }

  #pragma unroll
  for (int dt = 0; dt < 4; ++dt)
    #pragma unroll
    for (int r = 0; r < 4; ++r){
      int s = q0 + wid*16 + l4*4 + r;
      int col = h*64 + dt*16 + l15;
      float v = oacc[dt][r] / lrow[r];
      Ob[((size_t)(b*2048 + s))*1024 + col] = (short)f2bf(v);
    }
}

// ---------------- launch ----------------
extern "C" void kernel_launch(void* const* d_in, const int* in_sizes, int n_in,
                              void* d_out, int out_size, void* d_ws, size_t ws_size,
                              hipStream_t stream)
{
  const float* X  = (const float*)d_in[0];
  const float* Wq = (const float*)d_in[1];
  const float* Wk = (const float*)d_in[2];
  const float* Wv = (const float*)d_in[3];
  const float* bq = (const float*)d_in[4];
  const float* bk = (const float*)d_in[5];
  const float* bv = (const float*)d_in[6];
  const float* Wo = (const float*)d_in[7];
  const float* bo = (const float*)d_in[8];
  float* Out = (float*)d_out;

  char* ws = (char*)d_ws;
  short* Xbf  = (short*)(ws);
  short* Wp   = (short*)(ws + 16777216);
  short* WoT  = (short*)(ws + 23068672);
  short* Qb   = (short*)(ws + 25165824);
  short* Kb   = (short*)(ws + 41943040);
  short* Vtb  = (short*)(ws + 58720256);
  short* Ob   = (short*)(ws + 75497472);

  pack_x   <<<4096, 256, 0, stream>>>(X, Xbf);
  pack_wqkv<<<1536, 256, 0, stream>>>(Wq, Wk, Wv, Wp);
  pack_wo  <<< 512, 256, 0, stream>>>(Wo, WoT);

  gemm128<0><<<24*64, 256, 0, stream>>>(Xbf, Wp, bq, bk, bv, Qb, Kb, Vtb, nullptr);
  attn      <<<64*32, 256, 0, stream>>>(Qb, Kb, Vtb, Ob);
  gemm128<1><<< 8*64, 256, 0, stream>>>(Ob, WoT, bo, nullptr, nullptr,
                                        nullptr, nullptr, nullptr, Out);
}

// Round 3
// 219.016 us; speedup vs baseline: 1.8299x; 1.6323x over previous
//
#include <hip/hip_runtime.h>
#include <stdint.h>

// MHA fwd: B=4,S=2048,E=1024,H=16,D=64. fp32 in/out, bf16 MFMA internally.
// pack(X,W->bf16) -> GEMM1 (QKV; Q pre-scaled by 0.125*log2e, V stored transposed)
//   -> causal flash attn (swapped-QK^T, lane-local softmax) -> GEMM2 (out proj).

typedef float   f32x4  __attribute__((ext_vector_type(4)));
typedef __bf16  bf16x8 __attribute__((ext_vector_type(8)));
typedef short   short8 __attribute__((ext_vector_type(8)));
typedef unsigned short ushort4v __attribute__((ext_vector_type(4)));

typedef __attribute__((address_space(1))) void GV;
typedef __attribute__((address_space(3))) void LV;

#define DEVI static __device__ __forceinline__

DEVI unsigned short f2bf(float f){
  unsigned u = __float_as_uint(f);
  unsigned r = u + 0x7fffu + ((u>>16)&1u);
  return (unsigned short)(r>>16);
}

DEVI unsigned cvt_pk_bf16(float lo, float hi){
  unsigned r;
  asm("v_cvt_pk_bf16_f32 %0, %1, %2" : "=v"(r) : "v"(lo), "v"(hi));
  return r;
}

DEVI void gl_lds16(const void* g, void* l){
  __builtin_amdgcn_global_load_lds((GV*)g, (LV*)l, 16, 0, 0);
}

// ---------------- pack kernels ----------------
__global__ __launch_bounds__(256) void pack_x(const float* __restrict__ X,
                                              short* __restrict__ Xb){
  int i = blockIdx.x*256 + threadIdx.x;
  const float4* p = (const float4*)(X + (size_t)i*8);
  float4 a = p[0], b = p[1];
  short8 o;
  o[0]=(short)f2bf(a.x); o[1]=(short)f2bf(a.y); o[2]=(short)f2bf(a.z); o[3]=(short)f2bf(a.w);
  o[4]=(short)f2bf(b.x); o[5]=(short)f2bf(b.y); o[6]=(short)f2bf(b.z); o[7]=(short)f2bf(b.w);
  *(short8*)(Xb + (size_t)i*8) = o;
}

__global__ __launch_bounds__(256) void pack_wqkv(const float* __restrict__ Wq,
                                                 const float* __restrict__ Wk,
                                                 const float* __restrict__ Wv,
                                                 short* __restrict__ Wp){
  int t = blockIdx.x*256 + threadIdx.x;
  int n = t >> 7, kc = t & 127;
  int which = n >> 10, hd = n & 1023, h = hd >> 6, d = hd & 63;
  const float* W = which==0 ? Wq : (which==1 ? Wk : Wv);
  const float* src = W + ((size_t)h*1024 + kc*8)*64 + d;
  short8 o;
  #pragma unroll
  for (int j=0;j<8;++j) o[j] = (short)f2bf(src[(size_t)j*64]);
  *(short8*)(Wp + (size_t)n*1024 + kc*8) = o;
}

__global__ __launch_bounds__(256) void pack_wo(const float* __restrict__ Wo,
                                               short* __restrict__ WoT){
  int t = blockIdx.x*256 + threadIdx.x;
  int n = t >> 7, kc = t & 127;
  const float* src = Wo + (size_t)(kc*8)*1024 + n;
  short8 o;
  #pragma unroll
  for (int j=0;j<8;++j) o[j] = (short)f2bf(src[(size_t)j*1024]);
  *(short8*)(WoT + (size_t)n*1024 + kc*8) = o;
}

// ---------------- GEMM: C[M=8192][N] = A[M][1024] * Bt[N][1024]^T ----------------
template<int MODE>   // 0: QKV epilogue, 1: out-proj epilogue
__global__ __launch_bounds__(256)
void gemm128(const short* __restrict__ A, const short* __restrict__ Bt,
             const float* __restrict__ b0, const float* __restrict__ b1,
             const float* __restrict__ b2,
             short* __restrict__ Qb, short* __restrict__ Kb, short* __restrict__ Vtb,
             float* __restrict__ Out)
{
  __shared__ __align__(16) char smA[128*128];
  __shared__ __align__(16) char smB[128*128];
  const int K2 = 2048;
  int t = threadIdx.x, lane = t & 63, wid = t >> 6;
  int wr = wid >> 1, wc = wid & 1;
  int l15 = lane & 15, l4 = lane >> 4;
  int nwg = gridDim.x, qd = nwg >> 3;
  int swz = (blockIdx.x & 7) * qd + (blockIdx.x >> 3);
  int bm = swz & 63, bn = swz >> 6;
  size_t abase = (size_t)bm * 128 * K2;
  size_t bbase = (size_t)bn * 128 * K2;

  f32x4 acc[4][4] = {};

  for (int kt = 0; kt < 16; ++kt){
    int kb = kt * 128;
    #pragma unroll
    for (int c = 0; c < 4; ++c){
      int x = c*4096 + t*16;
      int r = x >> 7, z = x & 127;
      int zs = z ^ ((r & 7) << 4);
      gl_lds16((const char*)A  + abase + (size_t)r*K2 + kb + zs, smA + c*4096 + wid*1024);
      gl_lds16((const char*)Bt + bbase + (size_t)r*K2 + kb + zs, smB + c*4096 + wid*1024);
    }
    __syncthreads();
    #pragma unroll
    for (int kk = 0; kk < 2; ++kk){
      bf16x8 af[4], bfr[4];
      int cb = kk*64 + l4*16;
      #pragma unroll
      for (int i = 0; i < 4; ++i){
        int ra = wr*64 + i*16 + l15;
        af[i]  = *(const bf16x8*)(smA + ra*128 + (cb ^ ((ra&7)<<4)));
        int rb = wc*64 + i*16 + l15;
        bfr[i] = *(const bf16x8*)(smB + rb*128 + (cb ^ ((rb&7)<<4)));
      }
      __builtin_amdgcn_s_setprio(1);
      #pragma unroll
      for (int i = 0; i < 4; ++i)
        #pragma unroll
        for (int j = 0; j < 4; ++j)
          acc[i][j] = __builtin_amdgcn_mfma_f32_16x16x32_bf16(af[i], bfr[j], acc[i][j], 0, 0, 0);
      __builtin_amdgcn_s_setprio(0);
    }
    __syncthreads();
  }

  #pragma unroll
  for (int i = 0; i < 4; ++i){
    int mbase = bm*128 + wr*64 + i*16 + l4*4;
    #pragma unroll
    for (int j = 0; j < 4; ++j){
      int n = bn*128 + wc*64 + j*16 + l15;
      if (MODE == 0){
        int which = n >> 10, hd = n & 1023, h = hd >> 6, d = hd & 63;
        const float* bp = which==0 ? b0 : (which==1 ? b1 : b2);
        float bias = bp[hd];
        int b = mbase >> 11, sbase = mbase & 2047;
        size_t bh = (size_t)(b*16 + h);
        if (which == 2){
          ushort4v pv;
          #pragma unroll
          for (int r = 0; r < 4; ++r) pv[r] = f2bf(acc[i][j][r] + bias);
          *(ushort4v*)(Vtb + (bh*64 + d)*2048 + sbase) = pv;
        } else {
          short* dst = (which==0 ? Qb : Kb) + bh*2048*64;
          // Q pre-scaled by 1/sqrt(D) * log2(e) so attn exp uses exp2 directly
          float sc = which==0 ? 0.18033688f : 1.0f;
          #pragma unroll
          for (int r = 0; r < 4; ++r)
            dst[(size_t)(sbase + r)*64 + d] = (short)f2bf((acc[i][j][r] + bias) * sc);
        }
      } else {
        float bias = b0[n];
        #pragma unroll
        for (int r = 0; r < 4; ++r)
          Out[(size_t)(mbase + r)*1024 + n] = acc[i][j][r] + bias;
      }
    }
  }
}

// ---------------- causal flash attention (swapped QK^T) ----------------
// grid: 1024 blocks = 64 bh x 16 q-chunks of 128 rows; 4 waves x 32 q-rows.
// Swapped S^T = K.Q^T: lane holds 16 scores for one q-row -> in-register softmax.
// qb table pairs long+short chunks on the same CU (XCD round-robin), uniform 68 steps.
__global__ __launch_bounds__(256, 4)
void attn(const short* __restrict__ Qb, const short* __restrict__ Kb,
          const short* __restrict__ Vtb, short* __restrict__ Ob)
{
  __shared__ __align__(16) char smK[2][8192];
  __shared__ __align__(16) char smV[2][8192];
  __shared__ __align__(16) char smP[4][2048];
  int t = threadIdx.x, lane = t & 63, wid = t >> 6;
  int l15 = lane & 15, hi = lane >> 4;
  int hi16 = hi*16, hi4 = hi*4;
  int bh = blockIdx.x & 63;
  int j = blockIdx.x >> 6;
  int qb = (j < 8) ? (15 - j) : (j - 8);
  int b = bh >> 4, h = bh & 15;
  int q0 = qb * 128;
  int wq0 = q0 + wid * 32;
  const char* Qh = (const char*)(Qb + (size_t)bh*2048*64);
  const char* Kh = (const char*)(Kb + (size_t)bh*2048*64);
  const char* Vh = (const char*)(Vtb + (size_t)bh*64*2048);
  char* Pw = smP[wid];

  // Q fragments (B-operand): qf[qt][kk]
  bf16x8 qf[2][2];
  #pragma unroll
  for (int qt = 0; qt < 2; ++qt)
    #pragma unroll
    for (int kk = 0; kk < 2; ++kk)
      qf[qt][kk] = *(const bf16x8*)(Qh + (size_t)(wq0 + qt*16 + l15)*128 + kk*64 + hi16);

  f32x4 oacc[2][4] = {};
  float m[2] = {-1e30f, -1e30f}, l[2] = {0.f, 0.f};

  int nkt = 2*qb + 2;

  // prologue: stage tile 0 into buffer 0
  #pragma unroll
  for (int c = 0; c < 2; ++c){
    int x = c*4096 + t*16;
    int r = x >> 7, z = x & 127;
    int zs = z ^ ((r & 7) << 4);
    gl_lds16(Kh + (size_t)r*128 + zs, smK[0] + c*4096 + wid*1024);
    gl_lds16(Vh + (size_t)r*4096 + zs, smV[0] + c*4096 + wid*1024);
  }
  __syncthreads();

  for (int kt = 0; kt < nkt; ++kt){
    int cur = kt & 1;
    if (kt + 1 < nkt){
      int nxt = cur ^ 1;
      #pragma unroll
      for (int c = 0; c < 2; ++c){
        int x = c*4096 + t*16;
        int r = x >> 7, z = x & 127;
        int zs = z ^ ((r & 7) << 4);
        gl_lds16(Kh + (size_t)(kt+1)*8192 + (size_t)r*128 + zs, smK[nxt] + c*4096 + wid*1024);
        gl_lds16(Vh + (size_t)r*4096 + (size_t)(kt+1)*128 + zs, smV[nxt] + c*4096 + wid*1024);
      }
    }
    const char* Kc = smK[cur];
    const char* Vc = smV[cur];
    int kbase = kt * 64;

    #pragma unroll
    for (int qt = 0; qt < 2; ++qt){
      int qlo = wq0 + qt*16;
      if (kbase > qlo + 15) continue;          // fully masked q-tile

      // --- QK^T swapped: sa[nt] = S^T[k in tile][q=l15] ---
      f32x4 sa[4];
      __builtin_amdgcn_s_setprio(1);
      #pragma unroll
      for (int nt = 0; nt < 4; ++nt){
        f32x4 a = {};
        #pragma unroll
        for (int kk = 0; kk < 2; ++kk){
          int rk = nt*16 + l15;
          bf16x8 kf = *(const bf16x8*)(Kc + rk*128 + ((kk*64 + hi16) ^ ((rk&7)<<4)));
          a = __builtin_amdgcn_mfma_f32_16x16x32_bf16(kf, qf[qt][kk], a, 0, 0, 0);
        }
        sa[nt] = a;
      }
      __builtin_amdgcn_s_setprio(0);

      // --- causal mask (k > q) ---
      int qrow = qlo + l15;
      if (kbase + 63 > qlo){
        #pragma unroll
        for (int nt = 0; nt < 4; ++nt)
          #pragma unroll
          for (int r = 0; r < 4; ++r)
            if (kbase + nt*16 + hi4 + r > qrow) sa[nt][r] = -1e30f;
      }

      // --- softmax (lane-local row; reduce over hi via 2 shuffles) ---
      float pm = sa[0][0];
      #pragma unroll
      for (int nt = 0; nt < 4; ++nt)
        #pragma unroll
        for (int r = 0; r < 4; ++r) pm = fmaxf(pm, sa[nt][r]);
      pm = fmaxf(pm, __shfl_xor(pm, 16));
      pm = fmaxf(pm, __shfl_xor(pm, 32));
      float mq = m[qt];
      if (!__all(pm <= mq + 8.0f)){            // defer-max: rescale only on growth
        float mnew = fmaxf(mq, pm);
        float sc = exp2f(mq - mnew);
        l[qt] *= sc;
        #pragma unroll
        for (int dt = 0; dt < 4; ++dt) oacc[qt][dt] *= sc;
        m[qt] = mnew; mq = mnew;
      }
      float rs = 0.f;
      unsigned pw[8];
      #pragma unroll
      for (int nt = 0; nt < 4; ++nt){
        float p0 = exp2f(sa[nt][0] - mq);
        float p1 = exp2f(sa[nt][1] - mq);
        float p2 = exp2f(sa[nt][2] - mq);
        float p3 = exp2f(sa[nt][3] - mq);
        rs += (p0 + p1) + (p2 + p3);
        pw[nt*2]   = cvt_pk_bf16(p0, p1);
        pw[nt*2+1] = cvt_pk_bf16(p2, p3);
      }
      rs += __shfl_xor(rs, 16);
      rs += __shfl_xor(rs, 32);
      l[qt] += rs;

      // --- P write: 4 x ds_write_b64 into wave-private buffer ---
      {
        char* base = Pw + l15*128;
        int sw = (l15 & 7) << 4;
        #pragma unroll
        for (int nt = 0; nt < 4; ++nt){
          unsigned long long w = (unsigned long long)pw[nt*2] |
                                 ((unsigned long long)pw[nt*2+1] << 32);
          *(unsigned long long*)(base + ((nt*32 + hi*8) ^ sw)) = w;
        }
      }

      // --- PV: O^T[d][q] += V^T[d][k] . P^T[k][q] ---
      __builtin_amdgcn_s_setprio(1);
      #pragma unroll
      for (int kk = 0; kk < 2; ++kk){
        bf16x8 pf = *(const bf16x8*)(Pw + l15*128 + ((kk*64 + hi16) ^ ((l15&7)<<4)));
        #pragma unroll
        for (int dt = 0; dt < 4; ++dt){
          int rv = dt*16 + l15;
          bf16x8 vf = *(const bf16x8*)(Vc + rv*128 + ((kk*64 + hi16) ^ ((rv&7)<<4)));
          oacc[qt][dt] = __builtin_amdgcn_mfma_f32_16x16x32_bf16(vf, pf, oacc[qt][dt], 0, 0, 0);
        }
      }
      __builtin_amdgcn_s_setprio(0);
    }
    __syncthreads();
  }

  // write O (concat layout [b][s][h*64+d]) in bf16; O^T regs: d=dt*16+hi*4+r, q=l15
  #pragma unroll
  for (int qt = 0; qt < 2; ++qt){
    float inv = 1.0f / l[qt];
    int srow = wq0 + qt*16 + l15;
    size_t rb = ((size_t)(b*2048 + srow))*1024 + h*64 + hi4;
    #pragma unroll
    for (int dt = 0; dt < 4; ++dt){
      unsigned w0 = cvt_pk_bf16(oacc[qt][dt][0]*inv, oacc[qt][dt][1]*inv);
      unsigned w1 = cvt_pk_bf16(oacc[qt][dt][2]*inv, oacc[qt][dt][3]*inv);
      *(unsigned long long*)(Ob + rb + dt*16) =
          ((unsigned long long)w1 << 32) | (unsigned long long)w0;
    }
  }
}

// ---------------- launch ----------------
extern "C" void kernel_launch(void* const* d_in, const int* in_sizes, int n_in,
                              void* d_out, int out_size, void* d_ws, size_t ws_size,
                              hipStream_t stream)
{
  const float* X  = (const float*)d_in[0];
  const float* Wq = (const float*)d_in[1];
  const float* Wk = (const float*)d_in[2];
  const float* Wv = (const float*)d_in[3];
  const float* bq = (const float*)d_in[4];
  const float* bk = (const float*)d_in[5];
  const float* bv = (const float*)d_in[6];
  const float* Wo = (const float*)d_in[7];
  const float* bo = (const float*)d_in[8];
  float* Out = (float*)d_out;

  char* ws = (char*)d_ws;
  short* Xbf  = (short*)(ws);
  short* Wp   = (short*)(ws + 16777216);
  short* WoT  = (short*)(ws + 23068672);
  short* Qb   = (short*)(ws + 25165824);
  short* Kb   = (short*)(ws + 41943040);
  short* Vtb  = (short*)(ws + 58720256);
  short* Ob   = (short*)(ws + 75497472);

  pack_x   <<<4096, 256, 0, stream>>>(X, Xbf);
  pack_wqkv<<<1536, 256, 0, stream>>>(Wq, Wk, Wv, Wp);
  pack_wo  <<< 512, 256, 0, stream>>>(Wo, WoT);

  gemm128<0><<<24*64, 256, 0, stream>>>(Xbf, Wp, bq, bk, bv, Qb, Kb, Vtb, nullptr);
  attn      <<<64*16, 256, 0, stream>>>(Qb, Kb, Vtb, Ob);
  gemm128<1><<< 8*64, 256, 0, stream>>>(Ob, WoT, bo, nullptr, nullptr,
                                        nullptr, nullptr, nullptr, Out);
}

// Round 4
// 204.530 us; speedup vs baseline: 1.9595x; 1.0708x over previous
//
#include <hip/hip_runtime.h>
#include <stdint.h>

// MHA fwd: B=4,S=2048,E=1024,H=16,D=64. fp32 in/out, bf16 MFMA internally.
// pack(X,W->bf16) -> GEMM1 (QKV; Q pre-scaled by 0.125*log2e, V stored transposed)
//   -> causal flash attn (swapped-QK^T, lane-local softmax, MFMA row-sums)
//   -> GEMM2 (out proj). GEMMs: 128x256 tile, 8 waves, triple-buffered counted-vmcnt pipeline.

typedef float   f32x4  __attribute__((ext_vector_type(4)));
typedef __bf16  bf16x8 __attribute__((ext_vector_type(8)));
typedef short   short8 __attribute__((ext_vector_type(8)));
typedef unsigned short ushort4v __attribute__((ext_vector_type(4)));

typedef __attribute__((address_space(1))) void GV;
typedef __attribute__((address_space(3))) void LV;

#define DEVI static __device__ __forceinline__

DEVI unsigned short f2bf(float f){
  unsigned u = __float_as_uint(f);
  unsigned r = u + 0x7fffu + ((u>>16)&1u);
  return (unsigned short)(r>>16);
}

DEVI unsigned cvt_pk_bf16(float lo, float hi){
  unsigned r;
  asm("v_cvt_pk_bf16_f32 %0, %1, %2" : "=v"(r) : "v"(lo), "v"(hi));
  return r;
}

DEVI void gl_lds16(const void* g, void* l){
  __builtin_amdgcn_global_load_lds((GV*)g, (LV*)l, 16, 0, 0);
}

// ---------------- pack kernels ----------------
__global__ __launch_bounds__(256) void pack_x(const float* __restrict__ X,
                                              short* __restrict__ Xb){
  int i = blockIdx.x*256 + threadIdx.x;
  const float4* p = (const float4*)(X + (size_t)i*8);
  float4 a = p[0], b = p[1];
  short8 o;
  o[0]=(short)f2bf(a.x); o[1]=(short)f2bf(a.y); o[2]=(short)f2bf(a.z); o[3]=(short)f2bf(a.w);
  o[4]=(short)f2bf(b.x); o[5]=(short)f2bf(b.y); o[6]=(short)f2bf(b.z); o[7]=(short)f2bf(b.w);
  *(short8*)(Xb + (size_t)i*8) = o;
}

__global__ __launch_bounds__(256) void pack_wqkv(const float* __restrict__ Wq,
                                                 const float* __restrict__ Wk,
                                                 const float* __restrict__ Wv,
                                                 short* __restrict__ Wp){
  int t = blockIdx.x*256 + threadIdx.x;
  int n = t >> 7, kc = t & 127;
  int which = n >> 10, hd = n & 1023, h = hd >> 6, d = hd & 63;
  const float* W = which==0 ? Wq : (which==1 ? Wk : Wv);
  const float* src = W + ((size_t)h*1024 + kc*8)*64 + d;
  short8 o;
  #pragma unroll
  for (int j=0;j<8;++j) o[j] = (short)f2bf(src[(size_t)j*64]);
  *(short8*)(Wp + (size_t)n*1024 + kc*8) = o;
}

__global__ __launch_bounds__(256) void pack_wo(const float* __restrict__ Wo,
                                               short* __restrict__ WoT){
  int t = blockIdx.x*256 + threadIdx.x;
  int n = t >> 7, kc = t & 127;
  const float* src = Wo + (size_t)(kc*8)*1024 + n;
  short8 o;
  #pragma unroll
  for (int j=0;j<8;++j) o[j] = (short)f2bf(src[(size_t)j*1024]);
  *(short8*)(WoT + (size_t)n*1024 + kc*8) = o;
}

// ------- GEMM: C[M=8192][N] = A[M][1024]*Bt[N][1024]^T, 128x256 tile, BK=64 -------
// 8 waves (512 thr) in 2Mx4N; per-wave 64x64 out. Triple-buffered LDS (3x48KB),
// prefetch distance 2 K-steps, counted vmcnt (never 0 in main loop), raw barriers.
template<int MODE>   // 0: QKV epilogue, 1: out-proj epilogue
__global__ __launch_bounds__(512)
void gemm256(const short* __restrict__ A, const short* __restrict__ Bt,
             const float* __restrict__ b0, const float* __restrict__ b1,
             const float* __restrict__ b2,
             short* __restrict__ Qb, short* __restrict__ Kb, short* __restrict__ Vtb,
             float* __restrict__ Out)
{
  __shared__ __align__(16) char sm[3][49152];   // per buf: A 16KB | B 32KB
  const int K2 = 2048;
  int t = threadIdx.x, lane = t & 63, wid = t >> 6;
  int wr = wid >> 2, wc = wid & 3;
  int l15 = lane & 15, l4 = lane >> 4;
  int nwg = gridDim.x, qd = nwg >> 3;
  int swz = (blockIdx.x & 7) * qd + (blockIdx.x >> 3);
  int bm = swz & 63, bn = swz >> 6;
  size_t abase = (size_t)bm * 128 * K2;
  size_t bbase = (size_t)bn * 256 * K2;

  f32x4 acc[4][4] = {};

  auto stage = [&](int kt, char* buf){
    int kb = kt * 128;
    #pragma unroll
    for (int c = 0; c < 2; ++c){
      int x = c*8192 + t*16;
      int r = x >> 7, z = x & 127;
      int zs = z ^ ((r & 7) << 4);
      gl_lds16((const char*)A + abase + (size_t)r*K2 + kb + zs, buf + c*8192 + wid*1024);
    }
    #pragma unroll
    for (int c = 0; c < 4; ++c){
      int x = c*8192 + t*16;
      int r = x >> 7, z = x & 127;
      int zs = z ^ ((r & 7) << 4);
      gl_lds16((const char*)Bt + bbase + (size_t)r*K2 + kb + zs, buf + 16384 + c*8192 + wid*1024);
    }
  };

  auto compute = [&](const char* buf){
    const char* sA = buf;
    const char* sB = buf + 16384;
    #pragma unroll
    for (int kk = 0; kk < 2; ++kk){
      bf16x8 af[4], bfr[4];
      int cb = kk*64 + l4*16;
      #pragma unroll
      for (int i = 0; i < 4; ++i){
        int ra = wr*64 + i*16 + l15;
        af[i]  = *(const bf16x8*)(sA + ra*128 + (cb ^ ((ra&7)<<4)));
        int rb = wc*64 + i*16 + l15;
        bfr[i] = *(const bf16x8*)(sB + rb*128 + (cb ^ ((rb&7)<<4)));
      }
      __builtin_amdgcn_s_setprio(1);
      #pragma unroll
      for (int i = 0; i < 4; ++i)
        #pragma unroll
        for (int j = 0; j < 4; ++j)
          acc[i][j] = __builtin_amdgcn_mfma_f32_16x16x32_bf16(af[i], bfr[j], acc[i][j], 0, 0, 0);
      __builtin_amdgcn_s_setprio(0);
    }
  };

  // prologue: 2 K-steps in flight (12 loads/wave)
  stage(0, sm[0]);
  stage(1, sm[1]);
  for (int kt = 0; kt < 14; ++kt){
    stage(kt + 2, sm[(kt + 2) % 3]);
    // wait own oldest 6 loads (step kt's) + all-waves rendezvous
    asm volatile("s_waitcnt vmcnt(12)\n\ts_barrier" ::: "memory");
    compute(sm[kt % 3]);
    // protect buf (kt%3) from next iteration's staging until all waves done reading
    asm volatile("s_barrier" ::: "memory");
  }
  asm volatile("s_waitcnt vmcnt(6)\n\ts_barrier" ::: "memory");
  compute(sm[2]);
  asm volatile("s_waitcnt vmcnt(0)" ::: "memory");
  compute(sm[0]);

  #pragma unroll
  for (int i = 0; i < 4; ++i){
    int mbase = bm*128 + wr*64 + i*16 + l4*4;
    #pragma unroll
    for (int j = 0; j < 4; ++j){
      int n = bn*256 + wc*64 + j*16 + l15;
      if (MODE == 0){
        int which = n >> 10, hd = n & 1023, h = hd >> 6, d = hd & 63;
        const float* bp = which==0 ? b0 : (which==1 ? b1 : b2);
        float bias = bp[hd];
        int b = mbase >> 11, sbase = mbase & 2047;
        size_t bh = (size_t)(b*16 + h);
        if (which == 2){
          ushort4v pv;
          #pragma unroll
          for (int r = 0; r < 4; ++r) pv[r] = f2bf(acc[i][j][r] + bias);
          *(ushort4v*)(Vtb + (bh*64 + d)*2048 + sbase) = pv;
        } else {
          short* dst = (which==0 ? Qb : Kb) + bh*2048*64;
          // Q pre-scaled by 1/sqrt(D) * log2(e) so attn exp uses exp2 directly
          float sc = which==0 ? 0.18033688f : 1.0f;
          #pragma unroll
          for (int r = 0; r < 4; ++r)
            dst[(size_t)(sbase + r)*64 + d] = (short)f2bf((acc[i][j][r] + bias) * sc);
        }
      } else {
        float bias = b0[n];
        #pragma unroll
        for (int r = 0; r < 4; ++r)
          Out[(size_t)(mbase + r)*1024 + n] = acc[i][j][r] + bias;
      }
    }
  }
}

// ---------------- causal flash attention (swapped QK^T) ----------------
// grid: 1024 blocks = 64 bh x 16 q-chunks of 128 rows; 4 waves x 32 q-rows.
// Swapped S^T = K.Q^T: lane holds 16 scores for one q-row -> in-register softmax.
// Row-sum l computed by MFMA (all-ones A-operand) -> rescales with oacc for free.
__global__ __launch_bounds__(256, 4)
void attn(const short* __restrict__ Qb, const short* __restrict__ Kb,
          const short* __restrict__ Vtb, short* __restrict__ Ob)
{
  __shared__ __align__(16) char smK[2][8192];
  __shared__ __align__(16) char smV[2][8192];
  __shared__ __align__(16) char smP[4][2048];
  int t = threadIdx.x, lane = t & 63, wid = t >> 6;
  int l15 = lane & 15, hi = lane >> 4;
  int hi16 = hi*16, hi4 = hi*4;
  int bh = blockIdx.x & 63;
  int j = blockIdx.x >> 6;
  int qb = (j < 8) ? (15 - j) : (j - 8);
  int b = bh >> 4, h = bh & 15;
  int q0 = qb * 128;
  int wq0 = q0 + wid * 32;
  const char* Qh = (const char*)(Qb + (size_t)bh*2048*64);
  const char* Kh = (const char*)(Kb + (size_t)bh*2048*64);
  const char* Vh = (const char*)(Vtb + (size_t)bh*64*2048);
  char* Pw = smP[wid];

  bf16x8 vones;
  #pragma unroll
  for (int z = 0; z < 8; ++z) vones[z] = (__bf16)1.0f;

  bf16x8 qf[2][2];
  #pragma unroll
  for (int qt = 0; qt < 2; ++qt)
    #pragma unroll
    for (int kk = 0; kk < 2; ++kk)
      qf[qt][kk] = *(const bf16x8*)(Qh + (size_t)(wq0 + qt*16 + l15)*128 + kk*64 + hi16);

  f32x4 oacc[2][4] = {};
  f32x4 lacc[2] = {};
  float m[2] = {-1e30f, -1e30f};

  int nkt = 2*qb + 2;

  #pragma unroll
  for (int c = 0; c < 2; ++c){
    int x = c*4096 + t*16;
    int r = x >> 7, z = x & 127;
    int zs = z ^ ((r & 7) << 4);
    gl_lds16(Kh + (size_t)r*128 + zs, smK[0] + c*4096 + wid*1024);
    gl_lds16(Vh + (size_t)r*4096 + zs, smV[0] + c*4096 + wid*1024);
  }
  __syncthreads();

  for (int kt = 0; kt < nkt; ++kt){
    int cur = kt & 1;
    if (kt + 1 < nkt){
      int nxt = cur ^ 1;
      #pragma unroll
      for (int c = 0; c < 2; ++c){
        int x = c*4096 + t*16;
        int r = x >> 7, z = x & 127;
        int zs = z ^ ((r & 7) << 4);
        gl_lds16(Kh + (size_t)(kt+1)*8192 + (size_t)r*128 + zs, smK[nxt] + c*4096 + wid*1024);
        gl_lds16(Vh + (size_t)r*4096 + (size_t)(kt+1)*128 + zs, smV[nxt] + c*4096 + wid*1024);
      }
    }
    const char* Kc = smK[cur];
    const char* Vc = smV[cur];
    int kbase = kt * 64;

    #pragma unroll
    for (int qt = 0; qt < 2; ++qt){
      int qlo = wq0 + qt*16;
      if (kbase > qlo + 15) continue;          // fully masked q-tile

      // --- QK^T swapped: sa[nt] = S^T[k in tile][q=l15] ---
      f32x4 sa[4];
      __builtin_amdgcn_s_setprio(1);
      #pragma unroll
      for (int nt = 0; nt < 4; ++nt){
        f32x4 a = {};
        #pragma unroll
        for (int kk = 0; kk < 2; ++kk){
          int rk = nt*16 + l15;
          bf16x8 kf = *(const bf16x8*)(Kc + rk*128 + ((kk*64 + hi16) ^ ((rk&7)<<4)));
          a = __builtin_amdgcn_mfma_f32_16x16x32_bf16(kf, qf[qt][kk], a, 0, 0, 0);
        }
        sa[nt] = a;
      }
      __builtin_amdgcn_s_setprio(0);

      // --- causal mask (k > q) ---
      int qrow = qlo + l15;
      if (kbase + 63 > qlo){
        #pragma unroll
        for (int nt = 0; nt < 4; ++nt)
          #pragma unroll
          for (int r = 0; r < 4; ++r)
            if (kbase + nt*16 + hi4 + r > qrow) sa[nt][r] = -1e30f;
      }

      // --- softmax: max via max3 tree + 2 shuffles; defer-max rescale ---
      float pm;
      {
        float t0 = fmaxf(fmaxf(sa[0][0], sa[0][1]), sa[0][2]);
        float t1 = fmaxf(fmaxf(sa[0][3], sa[1][0]), sa[1][1]);
        float t2 = fmaxf(fmaxf(sa[1][2], sa[1][3]), sa[2][0]);
        float t3 = fmaxf(fmaxf(sa[2][1], sa[2][2]), sa[2][3]);
        float t4 = fmaxf(fmaxf(sa[3][0], sa[3][1]), sa[3][2]);
        float u0 = fmaxf(fmaxf(t0, t1), sa[3][3]);
        float u1 = fmaxf(fmaxf(t2, t3), t4);
        pm = fmaxf(u0, u1);
      }
      pm = fmaxf(pm, __shfl_xor(pm, 16));
      pm = fmaxf(pm, __shfl_xor(pm, 32));
      float mq = m[qt];
      if (!__all(pm <= mq + 8.0f)){
        float mnew = fmaxf(mq, pm);
        float sc = exp2f(mq - mnew);
        lacc[qt] *= sc;
        #pragma unroll
        for (int dt = 0; dt < 4; ++dt) oacc[qt][dt] *= sc;
        m[qt] = mnew; mq = mnew;
      }
      unsigned pw[8];
      #pragma unroll
      for (int nt = 0; nt < 4; ++nt){
        float p0 = exp2f(sa[nt][0] - mq);
        float p1 = exp2f(sa[nt][1] - mq);
        float p2 = exp2f(sa[nt][2] - mq);
        float p3 = exp2f(sa[nt][3] - mq);
        pw[nt*2]   = cvt_pk_bf16(p0, p1);
        pw[nt*2+1] = cvt_pk_bf16(p2, p3);
      }

      // --- P write: 4 x ds_write_b64 into wave-private buffer ---
      {
        char* base = Pw + l15*128;
        int sw = (l15 & 7) << 4;
        #pragma unroll
        for (int nt = 0; nt < 4; ++nt){
          unsigned long long w = (unsigned long long)pw[nt*2] |
                                 ((unsigned long long)pw[nt*2+1] << 32);
          *(unsigned long long*)(base + ((nt*32 + hi*8) ^ sw)) = w;
        }
      }

      // --- PV: O^T[d][q] += V^T[d][k].P^T[k][q]; l = ones.P^T via MFMA ---
      __builtin_amdgcn_s_setprio(1);
      #pragma unroll
      for (int kk = 0; kk < 2; ++kk){
        bf16x8 pf = *(const bf16x8*)(Pw + l15*128 + ((kk*64 + hi16) ^ ((l15&7)<<4)));
        lacc[qt] = __builtin_amdgcn_mfma_f32_16x16x32_bf16(vones, pf, lacc[qt], 0, 0, 0);
        #pragma unroll
        for (int dt = 0; dt < 4; ++dt){
          int rv = dt*16 + l15;
          bf16x8 vf = *(const bf16x8*)(Vc + rv*128 + ((kk*64 + hi16) ^ ((rv&7)<<4)));
          oacc[qt][dt] = __builtin_amdgcn_mfma_f32_16x16x32_bf16(vf, pf, oacc[qt][dt], 0, 0, 0);
        }
      }
      __builtin_amdgcn_s_setprio(0);
    }
    __syncthreads();
  }

  // write O (concat layout [b][s][h*64+d]) in bf16; O^T regs: d=dt*16+hi*4+r, q=l15
  #pragma unroll
  for (int qt = 0; qt < 2; ++qt){
    float inv = 1.0f / lacc[qt][0];
    int srow = wq0 + qt*16 + l15;
    size_t rb = ((size_t)(b*2048 + srow))*1024 + h*64 + hi4;
    #pragma unroll
    for (int dt = 0; dt < 4; ++dt){
      unsigned w0 = cvt_pk_bf16(oacc[qt][dt][0]*inv, oacc[qt][dt][1]*inv);
      unsigned w1 = cvt_pk_bf16(oacc[qt][dt][2]*inv, oacc[qt][dt][3]*inv);
      *(unsigned long long*)(Ob + rb + dt*16) =
          ((unsigned long long)w1 << 32) | (unsigned long long)w0;
    }
  }
}

// ---------------- launch ----------------
extern "C" void kernel_launch(void* const* d_in, const int* in_sizes, int n_in,
                              void* d_out, int out_size, void* d_ws, size_t ws_size,
                              hipStream_t stream)
{
  const float* X  = (const float*)d_in[0];
  const float* Wq = (const float*)d_in[1];
  const float* Wk = (const float*)d_in[2];
  const float* Wv = (const float*)d_in[3];
  const float* bq = (const float*)d_in[4];
  const float* bk = (const float*)d_in[5];
  const float* bv = (const float*)d_in[6];
  const float* Wo = (const float*)d_in[7];
  const float* bo = (const float*)d_in[8];
  float* Out = (float*)d_out;

  char* ws = (char*)d_ws;
  short* Xbf  = (short*)(ws);
  short* Wp   = (short*)(ws + 16777216);
  short* WoT  = (short*)(ws + 23068672);
  short* Qb   = (short*)(ws + 25165824);
  short* Kb   = (short*)(ws + 41943040);
  short* Vtb  = (short*)(ws + 58720256);
  short* Ob   = (short*)(ws + 75497472);

  pack_x   <<<4096, 256, 0, stream>>>(X, Xbf);
  pack_wqkv<<<1536, 256, 0, stream>>>(Wq, Wk, Wv, Wp);
  pack_wo  <<< 512, 256, 0, stream>>>(Wo, WoT);

  gemm256<0><<<768, 512, 0, stream>>>(Xbf, Wp, bq, bk, bv, Qb, Kb, Vtb, nullptr);
  attn      <<<64*16, 256, 0, stream>>>(Qb, Kb, Vtb, Ob);
  gemm256<1><<<256, 512, 0, stream>>>(Ob, WoT, bo, nullptr, nullptr,
                                      nullptr, nullptr, nullptr, Out);
}

// Round 5
// 196.720 us; speedup vs baseline: 2.0373x; 1.0397x over previous
//
#include <hip/hip_runtime.h>
#include <stdint.h>

// MHA fwd: B=4,S=2048,E=1024,H=16,D=64. fp32 in/out, bf16 MFMA internally.
// pack(X,W->bf16) -> GEMM1 (QKV; Q pre-scaled by 0.125*log2e, V stored transposed)
//   -> causal flash attn (swapped-QK^T, in-register P via permlane swaps, MFMA row-sums,
//      QBLK=64, 2048 blocks LPT, 5 blocks/CU) -> GEMM2 (out proj).

typedef float   f32x4  __attribute__((ext_vector_type(4)));
typedef __bf16  bf16x8 __attribute__((ext_vector_type(8)));
typedef short   short8 __attribute__((ext_vector_type(8)));
typedef unsigned short ushort4v __attribute__((ext_vector_type(4)));

typedef __attribute__((address_space(1))) void GV;
typedef __attribute__((address_space(3))) void LV;

#define DEVI static __device__ __forceinline__

DEVI unsigned short f2bf(float f){
  unsigned u = __float_as_uint(f);
  unsigned r = u + 0x7fffu + ((u>>16)&1u);
  return (unsigned short)(r>>16);
}

DEVI unsigned cvt_pk_bf16(float lo, float hi){
  unsigned r;
  asm("v_cvt_pk_bf16_f32 %0, %1, %2" : "=v"(r) : "v"(lo), "v"(hi));
  return r;
}

DEVI void permlane32_swap(unsigned &a, unsigned &b){
  asm volatile("v_permlane32_swap_b32 %0, %1" : "+v"(a), "+v"(b));
}
DEVI void permlane16_swap(unsigned &a, unsigned &b){
  asm volatile("v_permlane16_swap_b32 %0, %1" : "+v"(a), "+v"(b));
}

DEVI void gl_lds16(const void* g, void* l){
  __builtin_amdgcn_global_load_lds((GV*)g, (LV*)l, 16, 0, 0);
}

// ---------------- pack kernels ----------------
__global__ __launch_bounds__(256) void pack_x(const float* __restrict__ X,
                                              short* __restrict__ Xb){
  int i = blockIdx.x*256 + threadIdx.x;
  const float4* p = (const float4*)(X + (size_t)i*8);
  float4 a = p[0], b = p[1];
  short8 o;
  o[0]=(short)f2bf(a.x); o[1]=(short)f2bf(a.y); o[2]=(short)f2bf(a.z); o[3]=(short)f2bf(a.w);
  o[4]=(short)f2bf(b.x); o[5]=(short)f2bf(b.y); o[6]=(short)f2bf(b.z); o[7]=(short)f2bf(b.w);
  *(short8*)(Xb + (size_t)i*8) = o;
}

__global__ __launch_bounds__(256) void pack_wqkv(const float* __restrict__ Wq,
                                                 const float* __restrict__ Wk,
                                                 const float* __restrict__ Wv,
                                                 short* __restrict__ Wp){
  int t = blockIdx.x*256 + threadIdx.x;
  int n = t >> 7, kc = t & 127;
  int which = n >> 10, hd = n & 1023, h = hd >> 6, d = hd & 63;
  const float* W = which==0 ? Wq : (which==1 ? Wk : Wv);
  const float* src = W + ((size_t)h*1024 + kc*8)*64 + d;
  short8 o;
  #pragma unroll
  for (int j=0;j<8;++j) o[j] = (short)f2bf(src[(size_t)j*64]);
  *(short8*)(Wp + (size_t)n*1024 + kc*8) = o;
}

__global__ __launch_bounds__(256) void pack_wo(const float* __restrict__ Wo,
                                               short* __restrict__ WoT){
  int t = blockIdx.x*256 + threadIdx.x;
  int n = t >> 7, kc = t & 127;
  const float* src = Wo + (size_t)(kc*8)*1024 + n;
  short8 o;
  #pragma unroll
  for (int j=0;j<8;++j) o[j] = (short)f2bf(src[(size_t)j*1024]);
  *(short8*)(WoT + (size_t)n*1024 + kc*8) = o;
}

// ------- GEMM: C[M=8192][N] = A[M][1024]*Bt[N][1024]^T, 128x256 tile, BK=64 -------
template<int MODE>   // 0: QKV epilogue, 1: out-proj epilogue
__global__ __launch_bounds__(512)
void gemm256(const short* __restrict__ A, const short* __restrict__ Bt,
             const float* __restrict__ b0, const float* __restrict__ b1,
             const float* __restrict__ b2,
             short* __restrict__ Qb, short* __restrict__ Kb, short* __restrict__ Vtb,
             float* __restrict__ Out)
{
  __shared__ __align__(16) char sm[3][49152];   // per buf: A 16KB | B 32KB
  const int K2 = 2048;
  int t = threadIdx.x, lane = t & 63, wid = t >> 6;
  int wr = wid >> 2, wc = wid & 3;
  int l15 = lane & 15, l4 = lane >> 4;
  int nwg = gridDim.x, qd = nwg >> 3;
  int swz = (blockIdx.x & 7) * qd + (blockIdx.x >> 3);
  int bm = swz & 63, bn = swz >> 6;
  size_t abase = (size_t)bm * 128 * K2;
  size_t bbase = (size_t)bn * 256 * K2;

  f32x4 acc[4][4] = {};

  auto stage = [&](int kt, char* buf){
    int kb = kt * 128;
    #pragma unroll
    for (int c = 0; c < 2; ++c){
      int x = c*8192 + t*16;
      int r = x >> 7, z = x & 127;
      int zs = z ^ ((r & 7) << 4);
      gl_lds16((const char*)A + abase + (size_t)r*K2 + kb + zs, buf + c*8192 + wid*1024);
    }
    #pragma unroll
    for (int c = 0; c < 4; ++c){
      int x = c*8192 + t*16;
      int r = x >> 7, z = x & 127;
      int zs = z ^ ((r & 7) << 4);
      gl_lds16((const char*)Bt + bbase + (size_t)r*K2 + kb + zs, buf + 16384 + c*8192 + wid*1024);
    }
  };

  auto compute = [&](const char* buf){
    const char* sA = buf;
    const char* sB = buf + 16384;
    #pragma unroll
    for (int kk = 0; kk < 2; ++kk){
      bf16x8 af[4], bfr[4];
      int cb = kk*64 + l4*16;
      #pragma unroll
      for (int i = 0; i < 4; ++i){
        int ra = wr*64 + i*16 + l15;
        af[i]  = *(const bf16x8*)(sA + ra*128 + (cb ^ ((ra&7)<<4)));
        int rb = wc*64 + i*16 + l15;
        bfr[i] = *(const bf16x8*)(sB + rb*128 + (cb ^ ((rb&7)<<4)));
      }
      __builtin_amdgcn_s_setprio(1);
      #pragma unroll
      for (int i = 0; i < 4; ++i)
        #pragma unroll
        for (int j = 0; j < 4; ++j)
          acc[i][j] = __builtin_amdgcn_mfma_f32_16x16x32_bf16(af[i], bfr[j], acc[i][j], 0, 0, 0);
      __builtin_amdgcn_s_setprio(0);
    }
  };

  stage(0, sm[0]);
  stage(1, sm[1]);
  for (int kt = 0; kt < 14; ++kt){
    stage(kt + 2, sm[(kt + 2) % 3]);
    asm volatile("s_waitcnt vmcnt(12)\n\ts_barrier" ::: "memory");
    compute(sm[kt % 3]);
    asm volatile("s_barrier" ::: "memory");
  }
  asm volatile("s_waitcnt vmcnt(6)\n\ts_barrier" ::: "memory");
  compute(sm[2]);
  asm volatile("s_waitcnt vmcnt(0)" ::: "memory");
  compute(sm[0]);

  #pragma unroll
  for (int i = 0; i < 4; ++i){
    int mbase = bm*128 + wr*64 + i*16 + l4*4;
    #pragma unroll
    for (int j = 0; j < 4; ++j){
      int n = bn*256 + wc*64 + j*16 + l15;
      if (MODE == 0){
        int which = n >> 10, hd = n & 1023, h = hd >> 6, d = hd & 63;
        const float* bp = which==0 ? b0 : (which==1 ? b1 : b2);
        float bias = bp[hd];
        int b = mbase >> 11, sbase = mbase & 2047;
        size_t bh = (size_t)(b*16 + h);
        if (which == 2){
          ushort4v pv;
          #pragma unroll
          for (int r = 0; r < 4; ++r) pv[r] = f2bf(acc[i][j][r] + bias);
          *(ushort4v*)(Vtb + (bh*64 + d)*2048 + sbase) = pv;
        } else {
          short* dst = (which==0 ? Qb : Kb) + bh*2048*64;
          float sc = which==0 ? 0.18033688f : 1.0f;
          #pragma unroll
          for (int r = 0; r < 4; ++r)
            dst[(size_t)(sbase + r)*64 + d] = (short)f2bf((acc[i][j][r] + bias) * sc);
        }
      } else {
        float bias = b0[n];
        #pragma unroll
        for (int r = 0; r < 4; ++r)
          Out[(size_t)(mbase + r)*1024 + n] = acc[i][j][r] + bias;
      }
    }
  }
}

// ---------------- causal flash attention (swapped QK^T, in-register P) ----------------
// grid: 2048 blocks = 32 q-chunks (LPT order) x 64 bh; 4 waves x 16 q-rows (QBLK=64).
// LDS 32KB (K/V dbuf only) -> 5 blocks/CU; oversubscribed grid refills CUs (no tail).
// P stays in registers: permlane32/16_swap reshapes scores into PV B-fragments.
__global__ __launch_bounds__(256, 5)
void attn(const short* __restrict__ Qb, const short* __restrict__ Kb,
          const short* __restrict__ Vtb, short* __restrict__ Ob)
{
  __shared__ __align__(16) char smK[2][8192];
  __shared__ __align__(16) char smV[2][8192];
  int t = threadIdx.x, lane = t & 63, wid = t >> 6;
  int l15 = lane & 15, hi = lane >> 4;
  int hi16 = hi*16, hi4 = hi*4;
  int bh = blockIdx.x & 63;
  int qb = 31 - (blockIdx.x >> 6);           // LPT: longest first
  int b = bh >> 4, h = bh & 15;
  int wq0 = qb*64 + wid*16;
  const char* Qh = (const char*)(Qb + (size_t)bh*2048*64);
  const char* Kh = (const char*)(Kb + (size_t)bh*2048*64);
  const char* Vh = (const char*)(Vtb + (size_t)bh*64*2048);

  bf16x8 vones;
  #pragma unroll
  for (int z = 0; z < 8; ++z) vones[z] = (__bf16)1.0f;

  bf16x8 qf[2];
  #pragma unroll
  for (int kk = 0; kk < 2; ++kk)
    qf[kk] = *(const bf16x8*)(Qh + (size_t)(wq0 + l15)*128 + kk*64 + hi16);

  f32x4 oacc[4] = {};
  f32x4 lacc = {};
  float m = -1e30f;

  int nkt = qb + 1;

  #pragma unroll
  for (int c = 0; c < 2; ++c){
    int x = c*4096 + t*16;
    int r = x >> 7, z = x & 127;
    int zs = z ^ ((r & 7) << 4);
    gl_lds16(Kh + (size_t)r*128 + zs, smK[0] + c*4096 + wid*1024);
    gl_lds16(Vh + (size_t)r*4096 + zs, smV[0] + c*4096 + wid*1024);
  }
  __syncthreads();

  for (int kt = 0; kt < nkt; ++kt){
    int cur = kt & 1;
    if (kt + 1 < nkt){
      int nxt = cur ^ 1;
      #pragma unroll
      for (int c = 0; c < 2; ++c){
        int x = c*4096 + t*16;
        int r = x >> 7, z = x & 127;
        int zs = z ^ ((r & 7) << 4);
        gl_lds16(Kh + (size_t)(kt+1)*8192 + (size_t)r*128 + zs, smK[nxt] + c*4096 + wid*1024);
        gl_lds16(Vh + (size_t)r*4096 + (size_t)(kt+1)*128 + zs, smV[nxt] + c*4096 + wid*1024);
      }
    }
    const char* Kc = smK[cur];
    const char* Vc = smV[cur];
    int kbase = kt * 64;

    // --- QK^T swapped: sa[nt] = S^T[k = kbase+nt*16+hi4+r][q = wq0+l15] ---
    f32x4 sa[4];
    __builtin_amdgcn_s_setprio(1);
    #pragma unroll
    for (int nt = 0; nt < 4; ++nt){
      f32x4 a = {};
      #pragma unroll
      for (int kk = 0; kk < 2; ++kk){
        int rk = nt*16 + l15;
        bf16x8 kf = *(const bf16x8*)(Kc + rk*128 + ((kk*64 + hi16) ^ ((rk&7)<<4)));
        a = __builtin_amdgcn_mfma_f32_16x16x32_bf16(kf, qf[kk], a, 0, 0, 0);
      }
      sa[nt] = a;
    }
    __builtin_amdgcn_s_setprio(0);

    // --- causal mask (only the diagonal step needs it) ---
    if (kt == qb){
      int qrow = wq0 + l15;
      #pragma unroll
      for (int nt = 0; nt < 4; ++nt)
        #pragma unroll
        for (int r = 0; r < 4; ++r)
          if (kbase + nt*16 + hi4 + r > qrow) sa[nt][r] = -1e30f;
    }

    // --- softmax: max3 tree + 2 shuffles; defer-max rescale ---
    float pm;
    {
      float t0 = fmaxf(fmaxf(sa[0][0], sa[0][1]), sa[0][2]);
      float t1 = fmaxf(fmaxf(sa[0][3], sa[1][0]), sa[1][1]);
      float t2 = fmaxf(fmaxf(sa[1][2], sa[1][3]), sa[2][0]);
      float t3 = fmaxf(fmaxf(sa[2][1], sa[2][2]), sa[2][3]);
      float t4 = fmaxf(fmaxf(sa[3][0], sa[3][1]), sa[3][2]);
      float u0 = fmaxf(fmaxf(t0, t1), sa[3][3]);
      float u1 = fmaxf(fmaxf(t2, t3), t4);
      pm = fmaxf(u0, u1);
    }
    pm = fmaxf(pm, __shfl_xor(pm, 16));
    pm = fmaxf(pm, __shfl_xor(pm, 32));
    if (!__all(pm <= m + 8.0f)){
      float mnew = fmaxf(m, pm);
      float sc = exp2f(m - mnew);
      lacc *= sc;
      #pragma unroll
      for (int dt = 0; dt < 4; ++dt) oacc[dt] *= sc;
      m = mnew;
    }
    unsigned pw[8];
    #pragma unroll
    for (int nt = 0; nt < 4; ++nt){
      float p0 = exp2f(sa[nt][0] - m);
      float p1 = exp2f(sa[nt][1] - m);
      float p2 = exp2f(sa[nt][2] - m);
      float p3 = exp2f(sa[nt][3] - m);
      pw[nt*2]   = cvt_pk_bf16(p0, p1);
      pw[nt*2+1] = cvt_pk_bf16(p2, p3);
    }

    // --- in-register P reshape -> PV B-fragments (k-major per lane) ---
    // target lane (q,hi) dword c must hold P[k=kk*32+hi*8+2c,2c+1][q]
    union U { unsigned u[4]; bf16x8 v; } f0, f1;
    {
      unsigned a0 = pw[0], b0v = pw[2];
      permlane32_swap(a0, b0v); permlane16_swap(a0, b0v);
      unsigned a1 = pw[1], b1v = pw[3];
      permlane32_swap(a1, b1v); permlane16_swap(a1, b1v);
      f0.u[0] = a0; f0.u[1] = a1; f0.u[2] = b0v; f0.u[3] = b1v;
      unsigned a2 = pw[4], b2v = pw[6];
      permlane32_swap(a2, b2v); permlane16_swap(a2, b2v);
      unsigned a3 = pw[5], b3v = pw[7];
      permlane32_swap(a3, b3v); permlane16_swap(a3, b3v);
      f1.u[0] = a2; f1.u[1] = a3; f1.u[2] = b2v; f1.u[3] = b3v;
    }

    // --- PV: O^T[d][q] += V^T[d][k].P^T[k][q]; l = ones.P^T via MFMA ---
    __builtin_amdgcn_s_setprio(1);
    #pragma unroll
    for (int kk = 0; kk < 2; ++kk){
      bf16x8 pf = kk ? f1.v : f0.v;
      lacc = __builtin_amdgcn_mfma_f32_16x16x32_bf16(vones, pf, lacc, 0, 0, 0);
      #pragma unroll
      for (int dt = 0; dt < 4; ++dt){
        int rv = dt*16 + l15;
        bf16x8 vf = *(const bf16x8*)(Vc + rv*128 + ((kk*64 + hi16) ^ ((rv&7)<<4)));
        oacc[dt] = __builtin_amdgcn_mfma_f32_16x16x32_bf16(vf, pf, oacc[dt], 0, 0, 0);
      }
    }
    __builtin_amdgcn_s_setprio(0);

    __syncthreads();
  }

  // write O (concat layout [b][s][h*64+d]) in bf16; O^T regs: d=dt*16+hi*4+r, q=l15
  float inv = 1.0f / lacc[0];
  int srow = wq0 + l15;
  size_t rb = ((size_t)(b*2048 + srow))*1024 + h*64 + hi4;
  #pragma unroll
  for (int dt = 0; dt < 4; ++dt){
    unsigned w0 = cvt_pk_bf16(oacc[dt][0]*inv, oacc[dt][1]*inv);
    unsigned w1 = cvt_pk_bf16(oacc[dt][2]*inv, oacc[dt][3]*inv);
    *(unsigned long long*)(Ob + rb + dt*16) =
        ((unsigned long long)w1 << 32) | (unsigned long long)w0;
  }
}

// ---------------- launch ----------------
extern "C" void kernel_launch(void* const* d_in, const int* in_sizes, int n_in,
                              void* d_out, int out_size, void* d_ws, size_t ws_size,
                              hipStream_t stream)
{
  const float* X  = (const float*)d_in[0];
  const float* Wq = (const float*)d_in[1];
  const float* Wk = (const float*)d_in[2];
  const float* Wv = (const float*)d_in[3];
  const float* bq = (const float*)d_in[4];
  const float* bk = (const float*)d_in[5];
  const float* bv = (const float*)d_in[6];
  const float* Wo = (const float*)d_in[7];
  const float* bo = (const float*)d_in[8];
  float* Out = (float*)d_out;

  char* ws = (char*)d_ws;
  short* Xbf  = (short*)(ws);
  short* Wp   = (short*)(ws + 16777216);
  short* WoT  = (short*)(ws + 23068672);
  short* Qb   = (short*)(ws + 25165824);
  short* Kb   = (short*)(ws + 41943040);
  short* Vtb  = (short*)(ws + 58720256);
  short* Ob   = (short*)(ws + 75497472);

  pack_x   <<<4096, 256, 0, stream>>>(X, Xbf);
  pack_wqkv<<<1536, 256, 0, stream>>>(Wq, Wk, Wv, Wp);
  pack_wo  <<< 512, 256, 0, stream>>>(Wo, WoT);

  gemm256<0><<<768, 512, 0, stream>>>(Xbf, Wp, bq, bk, bv, Qb, Kb, Vtb, nullptr);
  attn      <<<2048, 256, 0, stream>>>(Qb, Kb, Vtb, Ob);
  gemm256<1><<<256, 512, 0, stream>>>(Ob, WoT, bo, nullptr, nullptr,
                                      nullptr, nullptr, nullptr, Out);
}

// Round 6
// 194.352 us; speedup vs baseline: 2.0621x; 1.0122x over previous
//
#include <hip/hip_runtime.h>
#include <stdint.h>

// MHA fwd: B=4,S=2048,E=1024,H=16,D=64. fp32 in/out, bf16 MFMA internally.
// pack(X,W->bf16) -> GEMM1 (QKV; Q pre-scaled by 0.125*log2e, V stored transposed)
//   -> causal flash attn (swapped-QK^T, in-register P via permlane swaps)
//   -> GEMM2 (out proj).
// GEMMs: 128x256 tile, 8 waves, 3-buffer LDS, 4-phase/K-step interleave with
// counted vmcnt (T3+T4) and setprio on MFMA clusters (T5).

typedef float   f32x4  __attribute__((ext_vector_type(4)));
typedef __bf16  bf16x8 __attribute__((ext_vector_type(8)));
typedef short   short8 __attribute__((ext_vector_type(8)));
typedef unsigned short ushort4v __attribute__((ext_vector_type(4)));

typedef __attribute__((address_space(1))) void GV;
typedef __attribute__((address_space(3))) void LV;

#define DEVI static __device__ __forceinline__

DEVI unsigned short f2bf(float f){
  unsigned u = __float_as_uint(f);
  unsigned r = u + 0x7fffu + ((u>>16)&1u);
  return (unsigned short)(r>>16);
}

DEVI unsigned cvt_pk_bf16(float lo, float hi){
  unsigned r;
  asm("v_cvt_pk_bf16_f32 %0, %1, %2" : "=v"(r) : "v"(lo), "v"(hi));
  return r;
}

DEVI void permlane32_swap(unsigned &a, unsigned &b){
  asm volatile("v_permlane32_swap_b32 %0, %1" : "+v"(a), "+v"(b));
}
DEVI void permlane16_swap(unsigned &a, unsigned &b){
  asm volatile("v_permlane16_swap_b32 %0, %1" : "+v"(a), "+v"(b));
}

DEVI void gl_lds16(const void* g, void* l){
  __builtin_amdgcn_global_load_lds((GV*)g, (LV*)l, 16, 0, 0);
}

#define BAR() asm volatile("s_barrier" ::: "memory")

// ---------------- pack kernels ----------------
__global__ __launch_bounds__(256) void pack_x(const float* __restrict__ X,
                                              short* __restrict__ Xb){
  int i = blockIdx.x*256 + threadIdx.x;
  const float4* p = (const float4*)(X + (size_t)i*8);
  float4 a = p[0], b = p[1];
  short8 o;
  o[0]=(short)f2bf(a.x); o[1]=(short)f2bf(a.y); o[2]=(short)f2bf(a.z); o[3]=(short)f2bf(a.w);
  o[4]=(short)f2bf(b.x); o[5]=(short)f2bf(b.y); o[6]=(short)f2bf(b.z); o[7]=(short)f2bf(b.w);
  *(short8*)(Xb + (size_t)i*8) = o;
}

__global__ __launch_bounds__(256) void pack_wqkv(const float* __restrict__ Wq,
                                                 const float* __restrict__ Wk,
                                                 const float* __restrict__ Wv,
                                                 short* __restrict__ Wp){
  int t = blockIdx.x*256 + threadIdx.x;
  int n = t >> 7, kc = t & 127;
  int which = n >> 10, hd = n & 1023, h = hd >> 6, d = hd & 63;
  const float* W = which==0 ? Wq : (which==1 ? Wk : Wv);
  const float* src = W + ((size_t)h*1024 + kc*8)*64 + d;
  short8 o;
  #pragma unroll
  for (int j=0;j<8;++j) o[j] = (short)f2bf(src[(size_t)j*64]);
  *(short8*)(Wp + (size_t)n*1024 + kc*8) = o;
}

__global__ __launch_bounds__(256) void pack_wo(const float* __restrict__ Wo,
                                               short* __restrict__ WoT){
  int t = blockIdx.x*256 + threadIdx.x;
  int n = t >> 7, kc = t & 127;
  const float* src = Wo + (size_t)(kc*8)*1024 + n;
  short8 o;
  #pragma unroll
  for (int j=0;j<8;++j) o[j] = (short)f2bf(src[(size_t)j*1024]);
  *(short8*)(WoT + (size_t)n*1024 + kc*8) = o;
}

// ------- GEMM: C[M=8192][N] = A[M][1024]*Bt[N][1024]^T, 128x256 tile, BK=64 -------
// 8 waves in 2Mx4N; per-wave 64x64 out. 3-buffer LDS, prefetch distance 2,
// 4 phases per K-step: {ds_read subtile | stage issue | barrier | MFMA x8 | barrier}.
template<int MODE>   // 0: QKV epilogue, 1: out-proj epilogue
__global__ __launch_bounds__(512)
void gemm256(const short* __restrict__ A, const short* __restrict__ Bt,
             const float* __restrict__ b0, const float* __restrict__ b1,
             const float* __restrict__ b2,
             short* __restrict__ Qb, short* __restrict__ Kb, short* __restrict__ Vtb,
             float* __restrict__ Out)
{
  __shared__ __align__(16) char sm[3][49152];   // per buf: A 16KB | B 32KB
  const int K2 = 2048;
  int t = threadIdx.x, lane = t & 63, wid = t >> 6;
  int wr = wid >> 2, wc = wid & 3;
  int l15 = lane & 15, l4 = lane >> 4;
  int nwg = gridDim.x, qd = nwg >> 3;
  int swz = (blockIdx.x & 7) * qd + (blockIdx.x >> 3);
  int bm = swz & 63, bn = swz >> 6;
  size_t abase = (size_t)bm * 128 * K2;
  size_t bbase = (size_t)bn * 256 * K2;

  f32x4 acc[4][4] = {};
  const char* sA; const char* sB;
  bf16x8 af[4], bfr[4];

  auto stageA = [&](int kt, char* buf){
    int kb = kt * 128;
    #pragma unroll
    for (int c = 0; c < 2; ++c){
      int x = c*8192 + t*16;
      int r = x >> 7, z = x & 127;
      int zs = z ^ ((r & 7) << 4);
      gl_lds16((const char*)A + abase + (size_t)r*K2 + kb + zs, buf + c*8192 + wid*1024);
    }
  };
  auto stageB = [&](int kt, char* buf, int c0){
    int kb = kt * 128;
    #pragma unroll
    for (int c = 0; c < 2; ++c){
      int cc = c0 + c;
      int x = cc*8192 + t*16;
      int r = x >> 7, z = x & 127;
      int zs = z ^ ((r & 7) << 4);
      gl_lds16((const char*)Bt + bbase + (size_t)r*K2 + kb + zs, buf + 16384 + cc*8192 + wid*1024);
    }
  };
  auto rd_af = [&](int kk){
    int cb = kk*64 + l4*16;
    #pragma unroll
    for (int i = 0; i < 4; ++i){
      int ra = wr*64 + i*16 + l15;
      af[i] = *(const bf16x8*)(sA + ra*128 + (cb ^ ((ra&7)<<4)));
    }
  };
  auto rd_bf = [&](int kk, int j0){
    int cb = kk*64 + l4*16;
    #pragma unroll
    for (int j = 0; j < 2; ++j){
      int rb = wc*64 + (j0 + j)*16 + l15;
      bfr[j0 + j] = *(const bf16x8*)(sB + rb*128 + (cb ^ ((rb&7)<<4)));
    }
  };
  auto mm = [&](int j0){
    __builtin_amdgcn_s_setprio(1);
    #pragma unroll
    for (int i = 0; i < 4; ++i)
      #pragma unroll
      for (int j = 0; j < 2; ++j)
        acc[i][j0+j] = __builtin_amdgcn_mfma_f32_16x16x32_bf16(af[i], bfr[j0+j], acc[i][j0+j], 0, 0, 0);
    __builtin_amdgcn_s_setprio(0);
  };

  // prologue: 2 K-steps fully staged
  stageA(0, sm[0]); stageB(0, sm[0], 0); stageB(0, sm[0], 2);
  stageA(1, sm[1]); stageB(1, sm[1], 0); stageB(1, sm[1], 2);

  for (int kt = 0; kt < 16; ++kt){
    // buffer-ready wait: counted (6 = next tile's loads stay in flight)
    if (kt == 15) asm volatile("s_waitcnt vmcnt(0)" ::: "memory");
    else          asm volatile("s_waitcnt vmcnt(6)" ::: "memory");
    BAR();
    sA = sm[kt % 3]; sB = sA + 16384;
    char* nb = sm[(kt + 2) % 3];
    bool st = kt < 14;
    // ph0: A-frags + B[0,1] reads, stage A of kt+2
    rd_af(0); rd_bf(0, 0);
    if (st) stageA(kt + 2, nb);
    BAR(); mm(0); BAR();
    // ph1: B[2,3] reads, stage B half 1
    rd_bf(0, 2);
    if (st) stageB(kt + 2, nb, 0);
    BAR(); mm(2); BAR();
    // ph2: kk=1 A-frags + B[0,1], stage B half 2
    rd_af(1); rd_bf(1, 0);
    if (st) stageB(kt + 2, nb, 2);
    BAR(); mm(0); BAR();
    // ph3: kk=1 B[2,3]
    rd_bf(1, 2);
    BAR(); mm(2);
    // next iteration's entry barrier closes this K-step
  }

  #pragma unroll
  for (int i = 0; i < 4; ++i){
    int mbase = bm*128 + wr*64 + i*16 + l4*4;
    #pragma unroll
    for (int j = 0; j < 4; ++j){
      int n = bn*256 + wc*64 + j*16 + l15;
      if (MODE == 0){
        int which = n >> 10, hd = n & 1023, h = hd >> 6, d = hd & 63;
        const float* bp = which==0 ? b0 : (which==1 ? b1 : b2);
        float bias = bp[hd];
        int b = mbase >> 11, sbase = mbase & 2047;
        size_t bh = (size_t)(b*16 + h);
        if (which == 2){
          ushort4v pv;
          #pragma unroll
          for (int r = 0; r < 4; ++r) pv[r] = f2bf(acc[i][j][r] + bias);
          *(ushort4v*)(Vtb + (bh*64 + d)*2048 + sbase) = pv;
        } else {
          short* dst = (which==0 ? Qb : Kb) + bh*2048*64;
          float sc = which==0 ? 0.18033688f : 1.0f;
          #pragma unroll
          for (int r = 0; r < 4; ++r)
            dst[(size_t)(sbase + r)*64 + d] = (short)f2bf((acc[i][j][r] + bias) * sc);
        }
      } else {
        float bias = b0[n];
        #pragma unroll
        for (int r = 0; r < 4; ++r)
          Out[(size_t)(mbase + r)*1024 + n] = acc[i][j][r] + bias;
      }
    }
  }
}

// ---------------- causal flash attention (swapped QK^T, in-register P) ----------------
// grid: 2048 blocks = 32 q-chunks (LPT order) x 64 bh; 4 waves x 16 q-rows (QBLK=64).
// LDS 32KB (K/V dbuf only) -> 5 blocks/CU; oversubscribed grid refills CUs (no tail).
// P stays in registers: permlane32/16_swap reshapes scores into PV B-fragments.
__global__ __launch_bounds__(256, 5)
void attn(const short* __restrict__ Qb, const short* __restrict__ Kb,
          const short* __restrict__ Vtb, short* __restrict__ Ob)
{
  __shared__ __align__(16) char smK[2][8192];
  __shared__ __align__(16) char smV[2][8192];
  int t = threadIdx.x, lane = t & 63, wid = t >> 6;
  int l15 = lane & 15, hi = lane >> 4;
  int hi16 = hi*16, hi4 = hi*4;
  int bh = blockIdx.x & 63;
  int qb = 31 - (blockIdx.x >> 6);           // LPT: longest first
  int b = bh >> 4, h = bh & 15;
  int wq0 = qb*64 + wid*16;
  const char* Qh = (const char*)(Qb + (size_t)bh*2048*64);
  const char* Kh = (const char*)(Kb + (size_t)bh*2048*64);
  const char* Vh = (const char*)(Vtb + (size_t)bh*64*2048);

  bf16x8 vones;
  #pragma unroll
  for (int z = 0; z < 8; ++z) vones[z] = (__bf16)1.0f;

  bf16x8 qf[2];
  #pragma unroll
  for (int kk = 0; kk < 2; ++kk)
    qf[kk] = *(const bf16x8*)(Qh + (size_t)(wq0 + l15)*128 + kk*64 + hi16);

  f32x4 oacc[4] = {};
  f32x4 lacc = {};
  float m = -1e30f;

  int nkt = qb + 1;

  #pragma unroll
  for (int c = 0; c < 2; ++c){
    int x = c*4096 + t*16;
    int r = x >> 7, z = x & 127;
    int zs = z ^ ((r & 7) << 4);
    gl_lds16(Kh + (size_t)r*128 + zs, smK[0] + c*4096 + wid*1024);
    gl_lds16(Vh + (size_t)r*4096 + zs, smV[0] + c*4096 + wid*1024);
  }
  __syncthreads();

  for (int kt = 0; kt < nkt; ++kt){
    int cur = kt & 1;
    if (kt + 1 < nkt){
      int nxt = cur ^ 1;
      #pragma unroll
      for (int c = 0; c < 2; ++c){
        int x = c*4096 + t*16;
        int r = x >> 7, z = x & 127;
        int zs = z ^ ((r & 7) << 4);
        gl_lds16(Kh + (size_t)(kt+1)*8192 + (size_t)r*128 + zs, smK[nxt] + c*4096 + wid*1024);
        gl_lds16(Vh + (size_t)r*4096 + (size_t)(kt+1)*128 + zs, smV[nxt] + c*4096 + wid*1024);
      }
    }
    const char* Kc = smK[cur];
    const char* Vc = smV[cur];
    int kbase = kt * 64;

    // --- QK^T swapped: sa[nt] = S^T[k = kbase+nt*16+hi4+r][q = wq0+l15] ---
    f32x4 sa[4];
    __builtin_amdgcn_s_setprio(1);
    #pragma unroll
    for (int nt = 0; nt < 4; ++nt){
      f32x4 a = {};
      #pragma unroll
      for (int kk = 0; kk < 2; ++kk){
        int rk = nt*16 + l15;
        bf16x8 kf = *(const bf16x8*)(Kc + rk*128 + ((kk*64 + hi16) ^ ((rk&7)<<4)));
        a = __builtin_amdgcn_mfma_f32_16x16x32_bf16(kf, qf[kk], a, 0, 0, 0);
      }
      sa[nt] = a;
    }
    __builtin_amdgcn_s_setprio(0);

    // --- causal mask (only the diagonal step needs it) ---
    if (kt == qb){
      int qrow = wq0 + l15;
      #pragma unroll
      for (int nt = 0; nt < 4; ++nt)
        #pragma unroll
        for (int r = 0; r < 4; ++r)
          if (kbase + nt*16 + hi4 + r > qrow) sa[nt][r] = -1e30f;
    }

    // --- softmax: max3 tree + 2 shuffles; defer-max rescale ---
    float pm;
    {
      float t0 = fmaxf(fmaxf(sa[0][0], sa[0][1]), sa[0][2]);
      float t1 = fmaxf(fmaxf(sa[0][3], sa[1][0]), sa[1][1]);
      float t2 = fmaxf(fmaxf(sa[1][2], sa[1][3]), sa[2][0]);
      float t3 = fmaxf(fmaxf(sa[2][1], sa[2][2]), sa[2][3]);
      float t4 = fmaxf(fmaxf(sa[3][0], sa[3][1]), sa[3][2]);
      float u0 = fmaxf(fmaxf(t0, t1), sa[3][3]);
      float u1 = fmaxf(fmaxf(t2, t3), t4);
      pm = fmaxf(u0, u1);
    }
    pm = fmaxf(pm, __shfl_xor(pm, 16));
    pm = fmaxf(pm, __shfl_xor(pm, 32));
    if (!__all(pm <= m + 8.0f)){
      float mnew = fmaxf(m, pm);
      float sc = exp2f(m - mnew);
      lacc *= sc;
      #pragma unroll
      for (int dt = 0; dt < 4; ++dt) oacc[dt] *= sc;
      m = mnew;
    }
    unsigned pw[8];
    #pragma unroll
    for (int nt = 0; nt < 4; ++nt){
      float p0 = exp2f(sa[nt][0] - m);
      float p1 = exp2f(sa[nt][1] - m);
      float p2 = exp2f(sa[nt][2] - m);
      float p3 = exp2f(sa[nt][3] - m);
      pw[nt*2]   = cvt_pk_bf16(p0, p1);
      pw[nt*2+1] = cvt_pk_bf16(p2, p3);
    }

    // --- in-register P reshape -> PV B-fragments (k-major per lane) ---
    union U { unsigned u[4]; bf16x8 v; } f0, f1;
    {
      unsigned a0 = pw[0], b0v = pw[2];
      permlane32_swap(a0, b0v); permlane16_swap(a0, b0v);
      unsigned a1 = pw[1], b1v = pw[3];
      permlane32_swap(a1, b1v); permlane16_swap(a1, b1v);
      f0.u[0] = a0; f0.u[1] = a1; f0.u[2] = b0v; f0.u[3] = b1v;
      unsigned a2 = pw[4], b2v = pw[6];
      permlane32_swap(a2, b2v); permlane16_swap(a2, b2v);
      unsigned a3 = pw[5], b3v = pw[7];
      permlane32_swap(a3, b3v); permlane16_swap(a3, b3v);
      f1.u[0] = a2; f1.u[1] = a3; f1.u[2] = b2v; f1.u[3] = b3v;
    }

    // --- PV: O^T[d][q] += V^T[d][k].P^T[k][q]; l = ones.P^T via MFMA ---
    __builtin_amdgcn_s_setprio(1);
    #pragma unroll
    for (int kk = 0; kk < 2; ++kk){
      bf16x8 pf = kk ? f1.v : f0.v;
      lacc = __builtin_amdgcn_mfma_f32_16x16x32_bf16(vones, pf, lacc, 0, 0, 0);
      #pragma unroll
      for (int dt = 0; dt < 4; ++dt){
        int rv = dt*16 + l15;
        bf16x8 vf = *(const bf16x8*)(Vc + rv*128 + ((kk*64 + hi16) ^ ((rv&7)<<4)));
        oacc[dt] = __builtin_amdgcn_mfma_f32_16x16x32_bf16(vf, pf, oacc[dt], 0, 0, 0);
      }
    }
    __builtin_amdgcn_s_setprio(0);

    __syncthreads();
  }

  // write O (concat layout [b][s][h*64+d]) in bf16; O^T regs: d=dt*16+hi*4+r, q=l15
  float inv = 1.0f / lacc[0];
  int srow = wq0 + l15;
  size_t rb = ((size_t)(b*2048 + srow))*1024 + h*64 + hi4;
  #pragma unroll
  for (int dt = 0; dt < 4; ++dt){
    unsigned w0 = cvt_pk_bf16(oacc[dt][0]*inv, oacc[dt][1]*inv);
    unsigned w1 = cvt_pk_bf16(oacc[dt][2]*inv, oacc[dt][3]*inv);
    *(unsigned long long*)(Ob + rb + dt*16) =
        ((unsigned long long)w1 << 32) | (unsigned long long)w0;
  }
}

// ---------------- launch ----------------
extern "C" void kernel_launch(void* const* d_in, const int* in_sizes, int n_in,
                              void* d_out, int out_size, void* d_ws, size_t ws_size,
                              hipStream_t stream)
{
  const float* X  = (const float*)d_in[0];
  const float* Wq = (const float*)d_in[1];
  const float* Wk = (const float*)d_in[2];
  const float* Wv = (const float*)d_in[3];
  const float* bq = (const float*)d_in[4];
  const float* bk = (const float*)d_in[5];
  const float* bv = (const float*)d_in[6];
  const float* Wo = (const float*)d_in[7];
  const float* bo = (const float*)d_in[8];
  float* Out = (float*)d_out;

  char* ws = (char*)d_ws;
  short* Xbf  = (short*)(ws);
  short* Wp   = (short*)(ws + 16777216);
  short* WoT  = (short*)(ws + 23068672);
  short* Qb   = (short*)(ws + 25165824);
  short* Kb   = (short*)(ws + 41943040);
  short* Vtb  = (short*)(ws + 58720256);
  short* Ob   = (short*)(ws + 75497472);

  pack_x   <<<4096, 256, 0, stream>>>(X, Xbf);
  pack_wqkv<<<1536, 256, 0, stream>>>(Wq, Wk, Wv, Wp);
  pack_wo  <<< 512, 256, 0, stream>>>(Wo, WoT);

  gemm256<0><<<768, 512, 0, stream>>>(Xbf, Wp, bq, bk, bv, Qb, Kb, Vtb, nullptr);
  attn      <<<2048, 256, 0, stream>>>(Qb, Kb, Vtb, Ob);
  gemm256<1><<<256, 512, 0, stream>>>(Ob, WoT, bo, nullptr, nullptr,
                                      nullptr, nullptr, nullptr, Out);
}